// Round 3
// baseline (1661.777 us; speedup 1.0000x reference)
//
#include <hip/hip_runtime.h>
#include <hip/hip_bf16.h>

// ---------------------------------------------------------------------------
// GIN (3 layers, eps=0) + global mean pool + FC — bucketed LDS-scatter version.
//
// Round-2 lesson: per-node CSR build (fill) cost 127us: 1.6M random 4B writes
// -> 105MB of dirty-line traffic. Per-node CSR is overkill: aggregation only
// needs edges grouped by COARSE dst bucket (128 nodes), with dstLocal packed
// in the same int32 as src. Build = LDS histograms + tiny scan + LDS-cursor
// fill writing ~64B contiguous runs. Aggregation = per-bucket LDS accumulator
// (ds_add_f32), lane = feature dim.
//
//   L1: agg x in 9-dim space (x is 3.6MB -> L2-resident), fuse Lin 9->64+b+relu
//   L2: agg64(h1 bf16) -> buf2 f32 ; Linear 64->128 +b2,relu -> h2 bf16
//   L3: Linear 128->64 (h2 bf16 -> t3 bf16) ; agg64(t3) + b3,relu -> h3 f32
//   pool: batch sorted -> binary search, 1 block/graph ; FC 64->11
// ---------------------------------------------------------------------------

#define NBLK 128      // blocks for count/fill
#define CFBS 512      // threads for count/fill
#define RB   128      // nodes per bucket
#define NBMAX 1024    // max buckets (N <= 131072)
#define SCBS 1024     // scan chunk

__device__ inline float bf2f(unsigned short u) {
    return __uint_as_float((unsigned)u << 16);
}
__device__ inline unsigned short f2bf(float f) {
    unsigned x = __float_as_uint(f);
    return (unsigned short)((x + 0x7FFFu + ((x >> 16) & 1u)) >> 16);  // RNE
}

// ---- bucket build ---------------------------------------------------------

__global__ __launch_bounds__(CFBS) void count_kernel(
    const int* __restrict__ dst, int* __restrict__ cnt, int E, int NB)
{
    __shared__ int hist[NBMAX];
    int tid = threadIdx.x;
    for (int i = tid; i < NBMAX; i += CFBS) hist[i] = 0;
    __syncthreads();
    for (int e = blockIdx.x * CFBS + tid; e < E; e += NBLK * CFBS)
        atomicAdd(&hist[dst[e] >> 7], 1);
    __syncthreads();
    for (int b = tid; b < NB; b += CFBS)
        cnt[b * NBLK + blockIdx.x] = hist[b];
}

// exclusive scan over cnt[0..NT) -> ofs, chunked
__global__ __launch_bounds__(SCBS) void scan_k1(
    const int* __restrict__ cnt, int* __restrict__ ofs,
    int* __restrict__ part, int NT)
{
    __shared__ int tmp[SCBS];
    int i = blockIdx.x * SCBS + threadIdx.x;
    int v = (i < NT) ? cnt[i] : 0;
    tmp[threadIdx.x] = v;
    __syncthreads();
    for (int off = 1; off < SCBS; off <<= 1) {
        int t = (threadIdx.x >= off) ? tmp[threadIdx.x - off] : 0;
        __syncthreads();
        tmp[threadIdx.x] += t;
        __syncthreads();
    }
    if (i < NT) ofs[i] = tmp[threadIdx.x] - v;   // exclusive within chunk
    if (threadIdx.x == SCBS - 1) part[blockIdx.x] = tmp[threadIdx.x];
}

__global__ __launch_bounds__(SCBS) void scan_k2(int* __restrict__ part, int B)
{
    __shared__ int tmp[SCBS];
    int v = (threadIdx.x < B) ? part[threadIdx.x] : 0;
    tmp[threadIdx.x] = v;
    __syncthreads();
    for (int off = 1; off < SCBS; off <<= 1) {
        int t = (threadIdx.x >= off) ? tmp[threadIdx.x - off] : 0;
        __syncthreads();
        tmp[threadIdx.x] += t;
        __syncthreads();
    }
    if (threadIdx.x < B) part[threadIdx.x] = tmp[threadIdx.x] - v;
}

__global__ __launch_bounds__(SCBS) void scan_k3(
    int* __restrict__ ofs, const int* __restrict__ part, int NT)
{
    int i = blockIdx.x * SCBS + threadIdx.x;
    if (i < NT) ofs[i] += part[blockIdx.x];
}

// pack (dstLocal << 20) | src into pairs, grouped by bucket, runs per block
__global__ __launch_bounds__(CFBS) void fillp_kernel(
    const int* __restrict__ src, const int* __restrict__ dst,
    const int* __restrict__ ofs, int* __restrict__ pairs, int E, int NB)
{
    __shared__ int cur[NBMAX];
    int tid = threadIdx.x;
    for (int b = tid; b < NB; b += CFBS)
        cur[b] = ofs[b * NBLK + blockIdx.x];
    __syncthreads();
    for (int e = blockIdx.x * CFBS + tid; e < E; e += NBLK * CFBS) {
        int d = dst[e];
        int b = d >> 7, dl = d & 127;
        int pos = atomicAdd(&cur[b], 1);
        pairs[pos] = (dl << 20) | src[e];
    }
}

// ---- layer 1: 9-dim LDS scatter + fused Linear 9->64 + relu --------------

__global__ __launch_bounds__(512) void agg9_lin1_kernel(
    const float* __restrict__ x, const int* __restrict__ ofs,
    const int* __restrict__ pairs, const float* __restrict__ W1,
    const float* __restrict__ b1, unsigned short* __restrict__ h1,
    int N, int E, int NB)
{
    __shared__ float acc[RB][9];
    __shared__ float Wl[576];
    __shared__ float bl[64];
    int tid = threadIdx.x;
    int b = blockIdx.x, n0 = b << 7;
    for (int i = tid; i < 576; i += 512) Wl[i] = W1[i];
    if (tid < 64) bl[tid] = b1[tid];
    // self init: acc flat = x[n0*9 ..], zero past N
    float* af = &acc[0][0];
    for (int i = tid; i < RB * 9; i += 512) {
        int n = n0 + i / 9;
        af[i] = (n < N) ? x[(size_t)n0 * 9 + i] : 0.f;
    }
    __syncthreads();
    int e0 = ofs[b * NBLK], e1 = (b + 1 < NB) ? ofs[(b + 1) * NBLK] : E;
    int w = tid >> 6, lane = tid & 63;
    int es = lane / 9, k = lane - es * 9;   // 7 edges x 9 dims, lane 63 idle
    int len = e1 - e0, per = (len + 7) >> 3;
    int s = e0 + w * per;
    int t = min(s + per, e1);
    for (int i = s; i < t; i += 7) {
        int m = min(7, t - i);
        if (lane < 63 && es < m) {
            int p = pairs[i + es];
            int sn = p & 0xFFFFF, dl = p >> 20;
            atomicAdd(&acc[dl][k], x[(size_t)sn * 9 + k]);
        }
    }
    __syncthreads();
    int o = lane;
    for (int r = w; r < RB; r += 8) {
        int n = n0 + r;
        if (n < N) {
            float sv = bl[o];
            #pragma unroll
            for (int kk = 0; kk < 9; ++kk) sv += acc[r][kk] * Wl[o * 9 + kk];
            h1[(size_t)n * 64 + o] = f2bf(fmaxf(sv, 0.f));
        }
    }
}

// ---- 64-dim LDS scatter (bf16 rows in, f32 out) ---------------------------

template<bool BIAS_RELU>
__global__ __launch_bounds__(512) void agg64_kernel(
    const unsigned short* __restrict__ feat, const int* __restrict__ ofs,
    const int* __restrict__ pairs, const float* __restrict__ bias,
    float* __restrict__ out, int N, int E, int NB)
{
    __shared__ float acc[RB][64];
    int tid = threadIdx.x;
    int b = blockIdx.x, n0 = b << 7;
    int w = tid >> 6, lane = tid & 63;
    // self init
    for (int r = w; r < RB; r += 8) {
        int n = n0 + r;
        acc[r][lane] = (n < N) ? bf2f(feat[(size_t)n * 64 + lane]) : 0.f;
    }
    __syncthreads();
    int e0 = ofs[b * NBLK], e1 = (b + 1 < NB) ? ofs[(b + 1) * NBLK] : E;
    int len = e1 - e0, per = (len + 7) >> 3;
    int s = e0 + w * per;
    int t = min(s + per, e1);
    int i = s;
    for (; i + 4 <= t; i += 4) {
        int p0 = pairs[i], p1 = pairs[i + 1], p2 = pairs[i + 2], p3 = pairs[i + 3];
        float v0 = bf2f(feat[(size_t)(p0 & 0xFFFFF) * 64 + lane]);
        float v1 = bf2f(feat[(size_t)(p1 & 0xFFFFF) * 64 + lane]);
        float v2 = bf2f(feat[(size_t)(p2 & 0xFFFFF) * 64 + lane]);
        float v3 = bf2f(feat[(size_t)(p3 & 0xFFFFF) * 64 + lane]);
        atomicAdd(&acc[p0 >> 20][lane], v0);
        atomicAdd(&acc[p1 >> 20][lane], v1);
        atomicAdd(&acc[p2 >> 20][lane], v2);
        atomicAdd(&acc[p3 >> 20][lane], v3);
    }
    for (; i < t; ++i) {
        int p = pairs[i];
        float v = bf2f(feat[(size_t)(p & 0xFFFFF) * 64 + lane]);
        atomicAdd(&acc[p >> 20][lane], v);
    }
    __syncthreads();
    float bv = BIAS_RELU ? bias[lane] : 0.f;
    for (int r = w; r < RB; r += 8) {
        int n = n0 + r;
        if (n < N) {
            float v = acc[r][lane];
            out[(size_t)n * 64 + lane] = BIAS_RELU ? fmaxf(v + bv, 0.f) : v;
        }
    }
}

// ---- Linear: Y[n] = A[n] @ W^T (+bias)(relu). IT/OT: float or ushort(bf16)

template<typename IT, typename OT, int IN, int OUT, int NB_, bool RELU>
__global__ __launch_bounds__(256) void linear_kernel(
    const IT* __restrict__ A, const float* __restrict__ W,
    const float* __restrict__ bias, OT* __restrict__ Y, int N)
{
    constexpr int INP = IN + 4;
    constexpr int OT_ = OUT / 4;
    constexpr int NPT = (NB_ * OT_) / 256;
    __shared__ float Wl[IN][OUT];
    __shared__ float S[NB_][INP];
    int tid = threadIdx.x;
    for (int i = tid; i < IN * OUT; i += 256) {
        int k = i / OUT, o = i % OUT;
        Wl[k][o] = W[o * IN + k];
    }
    int n0 = blockIdx.x * NB_;
    for (int i = tid; i < NB_ * IN / 4; i += 256) {
        int idx = i * 4;
        int node = idx / IN, k = idx % IN;
        int gn = n0 + node;
        float4 v = make_float4(0.f, 0.f, 0.f, 0.f);
        if (gn < N) {
            if constexpr (sizeof(IT) == 4) {
                v = *(const float4*)&A[(size_t)gn * IN + k];
            } else {
                ushort4 u = *(const ushort4*)&A[(size_t)gn * IN + k];
                v = make_float4(bf2f(u.x), bf2f(u.y), bf2f(u.z), bf2f(u.w));
            }
        }
        *(float4*)&S[node][k] = v;
    }
    __syncthreads();
    int ot = (tid % OT_) * 4;
    int nt = (tid / OT_) * NPT;
    float acc[NPT][4];
    #pragma unroll
    for (int i = 0; i < NPT; ++i)
        acc[i][0] = acc[i][1] = acc[i][2] = acc[i][3] = 0.f;
    #pragma unroll 4
    for (int k = 0; k < IN; ++k) {
        float4 wv = *(const float4*)&Wl[k][ot];
        #pragma unroll
        for (int i = 0; i < NPT; ++i) {
            float a = S[nt + i][k];
            acc[i][0] += a * wv.x; acc[i][1] += a * wv.y;
            acc[i][2] += a * wv.z; acc[i][3] += a * wv.w;
        }
    }
    float4 bv = make_float4(0.f, 0.f, 0.f, 0.f);
    if (bias) bv = *(const float4*)&bias[ot];
    #pragma unroll
    for (int i = 0; i < NPT; ++i) {
        int gn = n0 + nt + i;
        if (gn < N) {
            float r0 = acc[i][0] + bv.x, r1 = acc[i][1] + bv.y;
            float r2 = acc[i][2] + bv.z, r3 = acc[i][3] + bv.w;
            if (RELU) {
                r0 = fmaxf(r0, 0.f); r1 = fmaxf(r1, 0.f);
                r2 = fmaxf(r2, 0.f); r3 = fmaxf(r3, 0.f);
            }
            if constexpr (sizeof(OT) == 4) {
                *(float4*)&Y[(size_t)gn * OUT + ot] =
                    make_float4(r0, r1, r2, r3);
            } else {
                ushort4 u;
                u.x = f2bf(r0); u.y = f2bf(r1); u.z = f2bf(r2); u.w = f2bf(r3);
                *(ushort4*)&Y[(size_t)gn * OUT + ot] = u;
            }
        }
    }
}

// ---- pool + FC ------------------------------------------------------------

__device__ inline int lower_bound_i(const int* a, int n, int v) {
    int lo = 0, hi = n;
    while (lo < hi) {
        int mid = (lo + hi) >> 1;
        if (a[mid] < v) lo = mid + 1; else hi = mid;
    }
    return lo;
}

__global__ __launch_bounds__(256) void pool_fc_kernel(
    const float* __restrict__ h3, const int* __restrict__ batch,
    const float* __restrict__ Wfc, const float* __restrict__ bfc,
    float* __restrict__ out, int N)
{
    int g = blockIdx.x;
    int tid = threadIdx.x;
    int w = tid >> 6, lane = tid & 63;
    int lo = lower_bound_i(batch, N, g);
    int hi = lower_bound_i(batch, N, g + 1);
    float sum = 0.f;
    for (int i = lo + w; i < hi; i += 4) sum += h3[(size_t)i * 64 + lane];
    __shared__ float P[4][64];
    P[w][lane] = sum;
    __syncthreads();
    if (w == 0) {
        float s = P[0][lane] + P[1][lane] + P[2][lane] + P[3][lane];
        float cnt = (float)((hi - lo) > 0 ? (hi - lo) : 1);
        P[0][lane] = s / cnt;
    }
    __syncthreads();
    if (tid < 11) {
        float s = bfc[tid];
        const float* wr = &Wfc[tid * 64];
        #pragma unroll 8
        for (int k = 0; k < 64; ++k) s += P[0][k] * wr[k];
        out[g * 11 + tid] = s;
    }
}

// ---------------------------------------------------------------------------

extern "C" void kernel_launch(void* const* d_in, const int* in_sizes, int n_in,
                              void* d_out, int out_size, void* d_ws, size_t ws_size,
                              hipStream_t stream) {
    const float* x    = (const float*)d_in[0];
    const int*   ei   = (const int*)d_in[1];
    const int*   batch= (const int*)d_in[2];
    const float* W1   = (const float*)d_in[3];
    const float* b1   = (const float*)d_in[4];
    const float* W2   = (const float*)d_in[5];
    const float* b2   = (const float*)d_in[6];
    const float* W3   = (const float*)d_in[7];
    const float* b3   = (const float*)d_in[8];
    const float* Wfc  = (const float*)d_in[9];
    const float* bfc  = (const float*)d_in[10];
    float* out = (float*)d_out;

    const int N = in_sizes[2];
    const int E = in_sizes[1] / 2;
    const int G = out_size / 11;
    const int* src = ei;
    const int* dst = ei + E;
    const int NB = (N + RB - 1) / RB;      // buckets
    const int NT = NB * NBLK;              // count entries
    const int SB = (NT + SCBS - 1) / SCBS; // scan chunks

    // workspace:
    //   A0: 64N f32 (buf2 -> h3) | A1: 64N bf16 (h1 -> t3) | A2: 128N bf16 (h2)
    //   pairs: E i32 | cnt: NT i32 | ofs: NT i32 | part: SCBS i32
    float* A0 = (float*)d_ws;
    unsigned short* A1 = (unsigned short*)(A0 + (size_t)64 * N);
    unsigned short* A2 = A1 + (size_t)64 * N;
    int* pairs = (int*)(A2 + (size_t)128 * N);
    int* cnt  = pairs + E;
    int* ofs  = cnt + NT;
    int* part = ofs + NT;

    unsigned short* h1 = A1;
    float*          buf2 = A0;
    unsigned short* h2 = A2;
    unsigned short* t3 = A1;   // h1 dead after agg2
    float*          h3 = A0;   // buf2 dead after lin2

    // ---- bucket build ----
    count_kernel<<<NBLK, CFBS, 0, stream>>>(dst, cnt, E, NB);
    scan_k1<<<SB, SCBS, 0, stream>>>(cnt, ofs, part, NT);
    scan_k2<<<1, SCBS, 0, stream>>>(part, SB);
    scan_k3<<<SB, SCBS, 0, stream>>>(ofs, part, NT);
    fillp_kernel<<<NBLK, CFBS, 0, stream>>>(src, dst, ofs, pairs, E, NB);

    // ---- layer 1: agg9 + fused Linear 9->64 + relu -> h1 (bf16) ----
    agg9_lin1_kernel<<<NB, 512, 0, stream>>>(x, ofs, pairs, W1, b1, h1, N, E, NB);

    // ---- layer 2 ----
    agg64_kernel<false><<<NB, 512, 0, stream>>>(h1, ofs, pairs, nullptr, buf2, N, E, NB);
    linear_kernel<float, unsigned short, 64, 128, 32, true>
        <<<(N + 31) / 32, 256, 0, stream>>>(buf2, W2, b2, h2, N);

    // ---- layer 3 ----
    linear_kernel<unsigned short, unsigned short, 128, 64, 32, false>
        <<<(N + 31) / 32, 256, 0, stream>>>(h2, W3, nullptr, t3, N);
    agg64_kernel<true><<<NB, 512, 0, stream>>>(t3, ofs, pairs, b3, h3, N, E, NB);

    // ---- pool + FC ----
    pool_fc_kernel<<<G, 256, 0, stream>>>(h3, batch, Wfc, bfc, out, N);
}

// Round 4
// 396.197 us; speedup vs baseline: 4.1943x; 4.1943x over previous
//
#include <hip/hip_runtime.h>
#include <hip/hip_bf16.h>

// ---------------------------------------------------------------------------
// GIN (3 layers, eps=0) + global mean pool + FC.
//
// Round-2 lesson: global f32 atomics & random 4B CSR fill writes cost 64B
//   dirty-line amplification (105MB for 6.4MB of eidx).
// Round-3 lesson: block-per-bucket LDS aggregation collapses wave-level MLP
//   (6.3k waves x serial 256-edge loops -> latency-bound, 2% HBM, 688us).
// This round: bucket-grouped pair build (contiguous-run writes, cheap) +
//   per-bucket CSR finalize (writes land in bucket-local ~8KB windows) +
//   wave-per-node bf16 gather (100k waves, unroll-4 -> deep MLP).
//
//   build: count -> scan -> fillp (pairs by bucket) -> bucket CSR (eidx,rowstart)
//   L1: fused gather9(x, L2-resident) + Linear 9->64 + relu -> h1 bf16
//   L2: gather64(h1) -> buf2 f32 ; Linear 64->128 +b2,relu -> h2 bf16
//   L3: Linear 128->64 (h2 -> t3 bf16) ; gather64(t3) +b3,relu -> h3 f32
//   pool: batch sorted -> binary search ; FC 64->11
// ---------------------------------------------------------------------------

#define NBLK 128      // blocks for count/fill
#define CFBS 512      // threads for count/fill
#define RB   128      // nodes per bucket
#define NBMAX 1024    // max buckets (N <= 131072)
#define SCBS 1024     // scan chunk

__device__ inline float bf2f(unsigned short u) {
    return __uint_as_float((unsigned)u << 16);
}
__device__ inline unsigned short f2bf(float f) {
    unsigned x = __float_as_uint(f);
    return (unsigned short)((x + 0x7FFFu + ((x >> 16) & 1u)) >> 16);  // RNE
}

// ---- bucket build ---------------------------------------------------------

__global__ __launch_bounds__(CFBS) void count_kernel(
    const int* __restrict__ dst, int* __restrict__ cnt, int E, int NB)
{
    __shared__ int hist[NBMAX];
    int tid = threadIdx.x;
    for (int i = tid; i < NBMAX; i += CFBS) hist[i] = 0;
    __syncthreads();
    for (int e = blockIdx.x * CFBS + tid; e < E; e += NBLK * CFBS)
        atomicAdd(&hist[dst[e] >> 7], 1);
    __syncthreads();
    for (int b = tid; b < NB; b += CFBS)
        cnt[b * NBLK + blockIdx.x] = hist[b];
}

__global__ __launch_bounds__(SCBS) void scan_k1(
    const int* __restrict__ cnt, int* __restrict__ ofs,
    int* __restrict__ part, int NT)
{
    __shared__ int tmp[SCBS];
    int i = blockIdx.x * SCBS + threadIdx.x;
    int v = (i < NT) ? cnt[i] : 0;
    tmp[threadIdx.x] = v;
    __syncthreads();
    for (int off = 1; off < SCBS; off <<= 1) {
        int t = (threadIdx.x >= off) ? tmp[threadIdx.x - off] : 0;
        __syncthreads();
        tmp[threadIdx.x] += t;
        __syncthreads();
    }
    if (i < NT) ofs[i] = tmp[threadIdx.x] - v;   // exclusive within chunk
    if (threadIdx.x == SCBS - 1) part[blockIdx.x] = tmp[threadIdx.x];
}

__global__ __launch_bounds__(SCBS) void scan_k2(int* __restrict__ part, int B)
{
    __shared__ int tmp[SCBS];
    int v = (threadIdx.x < B) ? part[threadIdx.x] : 0;
    tmp[threadIdx.x] = v;
    __syncthreads();
    for (int off = 1; off < SCBS; off <<= 1) {
        int t = (threadIdx.x >= off) ? tmp[threadIdx.x - off] : 0;
        __syncthreads();
        tmp[threadIdx.x] += t;
        __syncthreads();
    }
    if (threadIdx.x < B) part[threadIdx.x] = tmp[threadIdx.x] - v;
}

__global__ __launch_bounds__(SCBS) void scan_k3(
    int* __restrict__ ofs, const int* __restrict__ part, int NT)
{
    int i = blockIdx.x * SCBS + threadIdx.x;
    if (i < NT) ofs[i] += part[blockIdx.x];
}

// pack (dstLocal << 20) | src into pairs, grouped by bucket, runs per block
__global__ __launch_bounds__(CFBS) void fillp_kernel(
    const int* __restrict__ src, const int* __restrict__ dst,
    const int* __restrict__ ofs, int* __restrict__ pairs, int E, int NB)
{
    __shared__ int cur[NBMAX];
    int tid = threadIdx.x;
    for (int b = tid; b < NB; b += CFBS)
        cur[b] = ofs[b * NBLK + blockIdx.x];
    __syncthreads();
    for (int e = blockIdx.x * CFBS + tid; e < E; e += NBLK * CFBS) {
        int d = dst[e];
        int b = d >> 7, dl = d & 127;
        int pos = atomicAdd(&cur[b], 1);
        pairs[pos] = (dl << 20) | src[e];
    }
}

// per-bucket CSR finalize: local degree hist + scan + scatter into eidx.
// All eidx writes fall in this bucket's contiguous [e0,e1) window.
__global__ __launch_bounds__(256) void bucket_csr_kernel(
    const int* __restrict__ pairs, const int* __restrict__ ofs,
    int* __restrict__ rowstart, int* __restrict__ eidx, int N, int E, int NB)
{
    __shared__ int deg[RB], pfx[RB], cur[RB];
    int tid = threadIdx.x;
    int b = blockIdx.x, n0 = b << 7;
    int e0 = ofs[b * NBLK];
    int e1 = (b + 1 < NB) ? ofs[(b + 1) * NBLK] : E;
    if (tid < RB) deg[tid] = 0;
    __syncthreads();
    for (int e = e0 + tid; e < e1; e += 256)
        atomicAdd(&deg[pairs[e] >> 20], 1);
    __syncthreads();
    if (tid < RB) pfx[tid] = deg[tid];
    __syncthreads();
    for (int off = 1; off < RB; off <<= 1) {
        int t = (tid < RB && tid >= off) ? pfx[tid - off] : 0;
        __syncthreads();
        if (tid < RB) pfx[tid] += t;
        __syncthreads();
    }
    if (tid < RB) {
        int ex = pfx[tid] - deg[tid];     // exclusive
        cur[tid] = ex;
        int n = n0 + tid;
        if (n < N) rowstart[n] = e0 + ex;
    }
    if (b == NB - 1 && tid == 0) rowstart[N] = E;
    __syncthreads();
    for (int e = e0 + tid; e < e1; e += 256) {
        int p = pairs[e];
        int pos = e0 + atomicAdd(&cur[p >> 20], 1);
        eidx[pos] = p & 0xFFFFF;
    }
}

// ---- layer 1: fused 9-dim gather + Linear 9->64 + relu -------------------
// One wave per node (4/block). x is 3.6MB -> L2/L3 resident.
__global__ __launch_bounds__(256) void node1_fused_kernel(
    const float* __restrict__ x, const int* __restrict__ rs,
    const int* __restrict__ eidx, const float* __restrict__ W1,
    const float* __restrict__ b1, unsigned short* __restrict__ h1, int N)
{
    __shared__ float Wl[576];
    __shared__ float bl[64];
    for (int i = threadIdx.x; i < 576; i += 256) Wl[i] = W1[i];
    if (threadIdx.x < 64) bl[threadIdx.x] = b1[threadIdx.x];
    __syncthreads();
    int n = blockIdx.x * 4 + (threadIdx.x >> 6);
    int lane = threadIdx.x & 63;
    if (n >= N) return;
    int e0 = rs[n], e1 = rs[n + 1];
    float a[9];
    #pragma unroll
    for (int k = 0; k < 9; ++k) a[k] = 0.f;
    for (int e = e0 + lane; e < e1; e += 64) {
        const float* xr = &x[(size_t)eidx[e] * 9];
        #pragma unroll
        for (int k = 0; k < 9; ++k) a[k] += xr[k];
    }
    if (lane == 0) {
        const float* xr = &x[(size_t)n * 9];
        #pragma unroll
        for (int k = 0; k < 9; ++k) a[k] += xr[k];
    }
    #pragma unroll
    for (int m = 32; m > 0; m >>= 1) {
        #pragma unroll
        for (int k = 0; k < 9; ++k) a[k] += __shfl_xor(a[k], m);
    }
    float s = bl[lane];
    const float* wr = &Wl[lane * 9];
    #pragma unroll
    for (int k = 0; k < 9; ++k) s += a[k] * wr[k];
    h1[(size_t)n * 64 + lane] = f2bf(fmaxf(s, 0.f));
}

// ---- 64-dim gather: out[n] = feat[n] + sum_in feat[src] (bf16 in, f32 out)
// Wave per node, lane = dim, 4 independent row loads in flight.
template<bool BIAS_RELU>
__global__ __launch_bounds__(256) void gather64_kernel(
    const unsigned short* __restrict__ feat, const int* __restrict__ rs,
    const int* __restrict__ eidx, const float* __restrict__ bias,
    float* __restrict__ out, int N)
{
    int n = blockIdx.x * 4 + (threadIdx.x >> 6);
    if (n >= N) return;
    int lane = threadIdx.x & 63;
    float a0 = bf2f(feat[(size_t)n * 64 + lane]);
    float a1 = 0.f, a2 = 0.f, a3 = 0.f;
    int e0 = rs[n], e1 = rs[n + 1];
    int e = e0;
    for (; e + 4 <= e1; e += 4) {
        int s0 = eidx[e], s1 = eidx[e + 1];
        int s2 = eidx[e + 2], s3 = eidx[e + 3];
        a0 += bf2f(feat[(size_t)s0 * 64 + lane]);
        a1 += bf2f(feat[(size_t)s1 * 64 + lane]);
        a2 += bf2f(feat[(size_t)s2 * 64 + lane]);
        a3 += bf2f(feat[(size_t)s3 * 64 + lane]);
    }
    for (; e < e1; ++e)
        a0 += bf2f(feat[(size_t)eidx[e] * 64 + lane]);
    float acc = (a0 + a1) + (a2 + a3);
    if (BIAS_RELU) acc = fmaxf(acc + bias[lane], 0.f);
    out[(size_t)n * 64 + lane] = acc;
}

// ---- Linear: Y[n] = A[n] @ W^T (+bias)(relu). IT/OT: float or ushort(bf16)

template<typename IT, typename OT, int IN, int OUT, int NB_, bool RELU>
__global__ __launch_bounds__(256) void linear_kernel(
    const IT* __restrict__ A, const float* __restrict__ W,
    const float* __restrict__ bias, OT* __restrict__ Y, int N)
{
    constexpr int INP = IN + 4;
    constexpr int OT_ = OUT / 4;
    constexpr int NPT = (NB_ * OT_) / 256;
    __shared__ float Wl[IN][OUT];
    __shared__ float S[NB_][INP];
    int tid = threadIdx.x;
    for (int i = tid; i < IN * OUT; i += 256) {
        int k = i / OUT, o = i % OUT;
        Wl[k][o] = W[o * IN + k];
    }
    int n0 = blockIdx.x * NB_;
    for (int i = tid; i < NB_ * IN / 4; i += 256) {
        int idx = i * 4;
        int node = idx / IN, k = idx % IN;
        int gn = n0 + node;
        float4 v = make_float4(0.f, 0.f, 0.f, 0.f);
        if (gn < N) {
            if constexpr (sizeof(IT) == 4) {
                v = *(const float4*)&A[(size_t)gn * IN + k];
            } else {
                ushort4 u = *(const ushort4*)&A[(size_t)gn * IN + k];
                v = make_float4(bf2f(u.x), bf2f(u.y), bf2f(u.z), bf2f(u.w));
            }
        }
        *(float4*)&S[node][k] = v;
    }
    __syncthreads();
    int ot = (tid % OT_) * 4;
    int nt = (tid / OT_) * NPT;
    float acc[NPT][4];
    #pragma unroll
    for (int i = 0; i < NPT; ++i)
        acc[i][0] = acc[i][1] = acc[i][2] = acc[i][3] = 0.f;
    #pragma unroll 4
    for (int k = 0; k < IN; ++k) {
        float4 wv = *(const float4*)&Wl[k][ot];
        #pragma unroll
        for (int i = 0; i < NPT; ++i) {
            float a = S[nt + i][k];
            acc[i][0] += a * wv.x; acc[i][1] += a * wv.y;
            acc[i][2] += a * wv.z; acc[i][3] += a * wv.w;
        }
    }
    float4 bv = make_float4(0.f, 0.f, 0.f, 0.f);
    if (bias) bv = *(const float4*)&bias[ot];
    #pragma unroll
    for (int i = 0; i < NPT; ++i) {
        int gn = n0 + nt + i;
        if (gn < N) {
            float r0 = acc[i][0] + bv.x, r1 = acc[i][1] + bv.y;
            float r2 = acc[i][2] + bv.z, r3 = acc[i][3] + bv.w;
            if (RELU) {
                r0 = fmaxf(r0, 0.f); r1 = fmaxf(r1, 0.f);
                r2 = fmaxf(r2, 0.f); r3 = fmaxf(r3, 0.f);
            }
            if constexpr (sizeof(OT) == 4) {
                *(float4*)&Y[(size_t)gn * OUT + ot] =
                    make_float4(r0, r1, r2, r3);
            } else {
                ushort4 u;
                u.x = f2bf(r0); u.y = f2bf(r1); u.z = f2bf(r2); u.w = f2bf(r3);
                *(ushort4*)&Y[(size_t)gn * OUT + ot] = u;
            }
        }
    }
}

// ---- pool + FC ------------------------------------------------------------

__device__ inline int lower_bound_i(const int* a, int n, int v) {
    int lo = 0, hi = n;
    while (lo < hi) {
        int mid = (lo + hi) >> 1;
        if (a[mid] < v) lo = mid + 1; else hi = mid;
    }
    return lo;
}

__global__ __launch_bounds__(256) void pool_fc_kernel(
    const float* __restrict__ h3, const int* __restrict__ batch,
    const float* __restrict__ Wfc, const float* __restrict__ bfc,
    float* __restrict__ out, int N)
{
    int g = blockIdx.x;
    int tid = threadIdx.x;
    int w = tid >> 6, lane = tid & 63;
    int lo = lower_bound_i(batch, N, g);
    int hi = lower_bound_i(batch, N, g + 1);
    float sum = 0.f;
    for (int i = lo + w; i < hi; i += 4) sum += h3[(size_t)i * 64 + lane];
    __shared__ float P[4][64];
    P[w][lane] = sum;
    __syncthreads();
    if (w == 0) {
        float s = P[0][lane] + P[1][lane] + P[2][lane] + P[3][lane];
        float cnt = (float)((hi - lo) > 0 ? (hi - lo) : 1);
        P[0][lane] = s / cnt;
    }
    __syncthreads();
    if (tid < 11) {
        float s = bfc[tid];
        const float* wr = &Wfc[tid * 64];
        #pragma unroll 8
        for (int k = 0; k < 64; ++k) s += P[0][k] * wr[k];
        out[g * 11 + tid] = s;
    }
}

// ---------------------------------------------------------------------------

extern "C" void kernel_launch(void* const* d_in, const int* in_sizes, int n_in,
                              void* d_out, int out_size, void* d_ws, size_t ws_size,
                              hipStream_t stream) {
    const float* x    = (const float*)d_in[0];
    const int*   ei   = (const int*)d_in[1];
    const int*   batch= (const int*)d_in[2];
    const float* W1   = (const float*)d_in[3];
    const float* b1   = (const float*)d_in[4];
    const float* W2   = (const float*)d_in[5];
    const float* b2   = (const float*)d_in[6];
    const float* W3   = (const float*)d_in[7];
    const float* b3   = (const float*)d_in[8];
    const float* Wfc  = (const float*)d_in[9];
    const float* bfc  = (const float*)d_in[10];
    float* out = (float*)d_out;

    const int N = in_sizes[2];
    const int E = in_sizes[1] / 2;
    const int G = out_size / 11;
    const int* src = ei;
    const int* dst = ei + E;
    const int NB = (N + RB - 1) / RB;      // buckets
    const int NT = NB * NBLK;              // count entries
    const int SB = (NT + SCBS - 1) / SCBS; // scan chunks

    // workspace:
    //   A0: 64N f32 (buf2 -> h3) | A1: 64N bf16 (h1 -> t3) | A2: 128N bf16 (h2)
    //   pairs E | eidx E | rowstart N+1 | cnt NT | ofs NT | part SCBS  (i32)
    float* A0 = (float*)d_ws;
    unsigned short* A1 = (unsigned short*)(A0 + (size_t)64 * N);
    unsigned short* A2 = A1 + (size_t)64 * N;
    int* pairs    = (int*)(A2 + (size_t)128 * N);
    int* eidx     = pairs + E;
    int* rowstart = eidx + E;
    int* cnt      = rowstart + (N + 1);
    int* ofs      = cnt + NT;
    int* part     = ofs + NT;

    unsigned short* h1 = A1;
    float*          buf2 = A0;
    unsigned short* h2 = A2;
    unsigned short* t3 = A1;   // h1 dead after gather2
    float*          h3 = A0;   // buf2 dead after lin2

    // ---- build: bucket-grouped pairs, then per-bucket CSR ----
    count_kernel<<<NBLK, CFBS, 0, stream>>>(dst, cnt, E, NB);
    scan_k1<<<SB, SCBS, 0, stream>>>(cnt, ofs, part, NT);
    scan_k2<<<1, SCBS, 0, stream>>>(part, SB);
    scan_k3<<<SB, SCBS, 0, stream>>>(ofs, part, NT);
    fillp_kernel<<<NBLK, CFBS, 0, stream>>>(src, dst, ofs, pairs, E, NB);
    bucket_csr_kernel<<<NB, 256, 0, stream>>>(pairs, ofs, rowstart, eidx, N, E, NB);

    // ---- layer 1 ----
    node1_fused_kernel<<<(N + 3) / 4, 256, 0, stream>>>(
        x, rowstart, eidx, W1, b1, h1, N);

    // ---- layer 2 ----
    gather64_kernel<false><<<(N + 3) / 4, 256, 0, stream>>>(
        h1, rowstart, eidx, nullptr, buf2, N);
    linear_kernel<float, unsigned short, 64, 128, 32, true>
        <<<(N + 31) / 32, 256, 0, stream>>>(buf2, W2, b2, h2, N);

    // ---- layer 3 ----
    linear_kernel<unsigned short, unsigned short, 128, 64, 32, false>
        <<<(N + 31) / 32, 256, 0, stream>>>(h2, W3, nullptr, t3, N);
    gather64_kernel<true><<<(N + 3) / 4, 256, 0, stream>>>(
        t3, rowstart, eidx, b3, h3, N);

    // ---- pool + FC ----
    pool_fc_kernel<<<G, 256, 0, stream>>>(h3, batch, Wfc, bfc, out, N);
}

// Round 5
// 344.618 us; speedup vs baseline: 4.8221x; 1.1497x over previous
//
#include <hip/hip_runtime.h>
#include <hip/hip_bf16.h>

// ---------------------------------------------------------------------------
// GIN (3 layers, eps=0) + global mean pool + FC.
//
// Lessons: r1 global f32 atomics = 64B-line write-through (1.6GB);
//   r2 per-node CSR fill = 105MB dirty lines; r3 block-per-bucket agg =
//   latency collapse (2% HBM); r4 wave-per-node works but lane=dim / 9-scalar
//   loads waste memory instructions (node1 77us, VALUBusy 31%).
// r5: vectorized lane maps. Rows are bf16; bf16->f32 unpack is shift/mask.
//   node1: 16 edge-grp x 4 dim-grp lanes, 1 uint2 load / 16 edges / lane.
//   gather64v: 4 edge-grp x 16 dim-grp lanes, uint2 loads, unroll 2.
//   All inter-kernel tables bf16 (h1, buf2, h2, t3, h3, xb).
// ---------------------------------------------------------------------------

#define NBLK 256      // blocks for count/fill
#define CFBS 512      // threads for count/fill
#define RB   128      // nodes per bucket
#define NBMAX 1024    // max buckets (N <= 131072)
#define SCBS 1024     // scan chunk

__device__ inline float bf2f(unsigned short u) {
    return __uint_as_float((unsigned)u << 16);
}
__device__ inline unsigned short f2bf(float f) {
    unsigned x = __float_as_uint(f);
    return (unsigned short)((x + 0x7FFFu + ((x >> 16) & 1u)) >> 16);  // RNE
}
__device__ inline float lo16(unsigned u) { return __uint_as_float(u << 16); }
__device__ inline float hi16(unsigned u) { return __uint_as_float(u & 0xFFFF0000u); }

// ---- bucket build ---------------------------------------------------------

__global__ __launch_bounds__(CFBS) void count_kernel(
    const int* __restrict__ dst, int* __restrict__ cnt, int E, int NB)
{
    __shared__ int hist[NBMAX];
    int tid = threadIdx.x;
    for (int i = tid; i < NBMAX; i += CFBS) hist[i] = 0;
    __syncthreads();
    for (int e = blockIdx.x * CFBS + tid; e < E; e += NBLK * CFBS)
        atomicAdd(&hist[dst[e] >> 7], 1);
    __syncthreads();
    for (int b = tid; b < NB; b += CFBS)
        cnt[b * NBLK + blockIdx.x] = hist[b];
}

__global__ __launch_bounds__(SCBS) void scan_k1(
    const int* __restrict__ cnt, int* __restrict__ ofs,
    int* __restrict__ part, int NT)
{
    __shared__ int tmp[SCBS];
    int i = blockIdx.x * SCBS + threadIdx.x;
    int v = (i < NT) ? cnt[i] : 0;
    tmp[threadIdx.x] = v;
    __syncthreads();
    for (int off = 1; off < SCBS; off <<= 1) {
        int t = (threadIdx.x >= off) ? tmp[threadIdx.x - off] : 0;
        __syncthreads();
        tmp[threadIdx.x] += t;
        __syncthreads();
    }
    if (i < NT) ofs[i] = tmp[threadIdx.x] - v;   // exclusive within chunk
    if (threadIdx.x == SCBS - 1) part[blockIdx.x] = tmp[threadIdx.x];
}

__global__ __launch_bounds__(SCBS) void scan_k2(int* __restrict__ part, int B)
{
    __shared__ int tmp[SCBS];
    int v = (threadIdx.x < B) ? part[threadIdx.x] : 0;
    tmp[threadIdx.x] = v;
    __syncthreads();
    for (int off = 1; off < SCBS; off <<= 1) {
        int t = (threadIdx.x >= off) ? tmp[threadIdx.x - off] : 0;
        __syncthreads();
        tmp[threadIdx.x] += t;
        __syncthreads();
    }
    if (threadIdx.x < B) part[threadIdx.x] = tmp[threadIdx.x] - v;
}

__global__ __launch_bounds__(SCBS) void scan_k3(
    int* __restrict__ ofs, const int* __restrict__ part, int NT)
{
    int i = blockIdx.x * SCBS + threadIdx.x;
    if (i < NT) ofs[i] += part[blockIdx.x];
}

__global__ __launch_bounds__(CFBS) void fillp_kernel(
    const int* __restrict__ src, const int* __restrict__ dst,
    const int* __restrict__ ofs, int* __restrict__ pairs, int E, int NB)
{
    __shared__ int cur[NBMAX];
    int tid = threadIdx.x;
    for (int b = tid; b < NB; b += CFBS)
        cur[b] = ofs[b * NBLK + blockIdx.x];
    __syncthreads();
    for (int e = blockIdx.x * CFBS + tid; e < E; e += NBLK * CFBS) {
        int d = dst[e];
        int b = d >> 7, dl = d & 127;
        int pos = atomicAdd(&cur[b], 1);
        pairs[pos] = (dl << 20) | src[e];
    }
}

// per-bucket CSR finalize: writes land in bucket-local contiguous windows
__global__ __launch_bounds__(512) void bucket_csr_kernel(
    const int* __restrict__ pairs, const int* __restrict__ ofs,
    int* __restrict__ rowstart, int* __restrict__ eidx, int N, int E, int NB)
{
    __shared__ int deg[RB], pfx[RB], cur[RB];
    int tid = threadIdx.x;
    int b = blockIdx.x, n0 = b << 7;
    int e0 = ofs[b * NBLK];
    int e1 = (b + 1 < NB) ? ofs[(b + 1) * NBLK] : E;
    if (tid < RB) deg[tid] = 0;
    __syncthreads();
    for (int e = e0 + tid; e < e1; e += 512)
        atomicAdd(&deg[pairs[e] >> 20], 1);
    __syncthreads();
    if (tid < RB) pfx[tid] = deg[tid];
    __syncthreads();
    for (int off = 1; off < RB; off <<= 1) {
        int t = (tid < RB && tid >= off) ? pfx[tid - off] : 0;
        __syncthreads();
        if (tid < RB) pfx[tid] += t;
        __syncthreads();
    }
    if (tid < RB) {
        int ex = pfx[tid] - deg[tid];     // exclusive
        cur[tid] = ex;
        int n = n0 + tid;
        if (n < N) rowstart[n] = e0 + ex;
    }
    if (b == NB - 1 && tid == 0) rowstart[N] = E;
    __syncthreads();
    for (int e = e0 + tid; e < e1; e += 512) {
        int p = pairs[e];
        int pos = e0 + atomicAdd(&cur[p >> 20], 1);
        eidx[pos] = p & 0xFFFFF;
    }
}

// ---- x prep: xb[N][16] bf16 (pad 9->16) ----------------------------------

__global__ __launch_bounds__(256) void xprep_kernel(
    const float* __restrict__ x, unsigned short* __restrict__ xb, int N)
{
    int n = blockIdx.x * 256 + threadIdx.x;
    if (n >= N) return;
    unsigned short r[16];
    #pragma unroll
    for (int k = 0; k < 9; ++k) r[k] = f2bf(x[(size_t)n * 9 + k]);
    #pragma unroll
    for (int k = 9; k < 16; ++k) r[k] = 0;
    uint4 u0, u1;
    u0.x = r[0] | ((unsigned)r[1] << 16);  u0.y = r[2] | ((unsigned)r[3] << 16);
    u0.z = r[4] | ((unsigned)r[5] << 16);  u0.w = r[6] | ((unsigned)r[7] << 16);
    u1.x = r[8] | ((unsigned)r[9] << 16);  u1.y = 0; u1.z = 0; u1.w = 0;
    *(uint4*)&xb[(size_t)n * 16]     = u0;
    *(uint4*)&xb[(size_t)n * 16 + 8] = u1;
}

// ---- layer 1: 9-dim gather (16 edge-grp x 4 dim-grp) + Lin 9->64 + relu --

__global__ __launch_bounds__(256) void node1v_kernel(
    const unsigned short* __restrict__ xb, const int* __restrict__ rs,
    const int* __restrict__ eidx, const float* __restrict__ W1,
    const float* __restrict__ b1, unsigned short* __restrict__ h1, int N)
{
    __shared__ float Wl[576];
    __shared__ float bl[64];
    for (int i = threadIdx.x; i < 576; i += 256) Wl[i] = W1[i];
    if (threadIdx.x < 64) bl[threadIdx.x] = b1[threadIdx.x];
    __syncthreads();
    int n = blockIdx.x * 4 + (threadIdx.x >> 6);
    if (n >= N) return;
    int lane = threadIdx.x & 63;
    int g  = lane >> 2;     // edge group 0..15
    int d4 = lane & 3;      // dims 4*d4 .. 4*d4+3
    float a0 = 0.f, a1 = 0.f, a2 = 0.f, a3 = 0.f;
    if (g == 0) {           // self term, added once by lanes 0..3
        uint2 u = *(const uint2*)&xb[(size_t)n * 16 + d4 * 4];
        a0 += lo16(u.x); a1 += hi16(u.x); a2 += lo16(u.y); a3 += hi16(u.y);
    }
    int e0 = rs[n], e1 = rs[n + 1];
    for (int e = e0; e < e1; e += 16) {
        int idx = e + g;
        if (idx < e1) {
            int s = eidx[idx];
            uint2 u = *(const uint2*)&xb[(size_t)s * 16 + d4 * 4];
            a0 += lo16(u.x); a1 += hi16(u.x); a2 += lo16(u.y); a3 += hi16(u.y);
        }
    }
    #pragma unroll
    for (int m = 4; m < 64; m <<= 1) {
        a0 += __shfl_xor(a0, m); a1 += __shfl_xor(a1, m);
        a2 += __shfl_xor(a2, m); a3 += __shfl_xor(a3, m);
    }
    // dim k total lives in lane (k>>2), register a[k&3]
    float xv[9];
    xv[0] = __shfl(a0, 0); xv[1] = __shfl(a1, 0); xv[2] = __shfl(a2, 0);
    xv[3] = __shfl(a3, 0); xv[4] = __shfl(a0, 1); xv[5] = __shfl(a1, 1);
    xv[6] = __shfl(a2, 1); xv[7] = __shfl(a3, 1); xv[8] = __shfl(a0, 2);
    float s = bl[lane];
    const float* wr = &Wl[lane * 9];
    #pragma unroll
    for (int k = 0; k < 9; ++k) s += xv[k] * wr[k];
    h1[(size_t)n * 64 + lane] = f2bf(fmaxf(s, 0.f));
}

// ---- 64-dim gather: 4 edge-grp x 16 dim-grp, uint2 loads, unroll 2 -------
// out[n] = feat[n] + sum_in feat[src]  (+bias, relu). bf16 in, OT out.

template<bool BIAS_RELU, typename OT>
__global__ __launch_bounds__(256) void gather64v_kernel(
    const unsigned short* __restrict__ feat, const int* __restrict__ rs,
    const int* __restrict__ eidx, const float* __restrict__ bias,
    OT* __restrict__ out, int N)
{
    int n = blockIdx.x * 4 + (threadIdx.x >> 6);
    if (n >= N) return;
    int lane = threadIdx.x & 63;
    int g  = lane >> 4;     // edge group 0..3
    int d4 = lane & 15;     // dims 4*d4 .. 4*d4+3
    float a0 = 0.f, a1 = 0.f, a2 = 0.f, a3 = 0.f;
    if (g == 0) {           // self term
        uint2 u = *(const uint2*)&feat[(size_t)n * 64 + d4 * 4];
        a0 += lo16(u.x); a1 += hi16(u.x); a2 += lo16(u.y); a3 += hi16(u.y);
    }
    int e0 = rs[n], e1 = rs[n + 1];
    int e = e0;
    for (; e + 8 <= e1; e += 8) {
        int sA = eidx[e + g];
        int sB = eidx[e + 4 + g];
        uint2 uA = *(const uint2*)&feat[(size_t)sA * 64 + d4 * 4];
        uint2 uB = *(const uint2*)&feat[(size_t)sB * 64 + d4 * 4];
        a0 += lo16(uA.x); a1 += hi16(uA.x); a2 += lo16(uA.y); a3 += hi16(uA.y);
        a0 += lo16(uB.x); a1 += hi16(uB.x); a2 += lo16(uB.y); a3 += hi16(uB.y);
    }
    for (; e < e1; e += 4) {
        int idx = e + g;
        if (idx < e1) {
            int s = eidx[idx];
            uint2 u = *(const uint2*)&feat[(size_t)s * 64 + d4 * 4];
            a0 += lo16(u.x); a1 += hi16(u.x); a2 += lo16(u.y); a3 += hi16(u.y);
        }
    }
    a0 += __shfl_xor(a0, 16); a1 += __shfl_xor(a1, 16);
    a2 += __shfl_xor(a2, 16); a3 += __shfl_xor(a3, 16);
    a0 += __shfl_xor(a0, 32); a1 += __shfl_xor(a1, 32);
    a2 += __shfl_xor(a2, 32); a3 += __shfl_xor(a3, 32);
    if (g == 0) {
        if (BIAS_RELU) {
            float4 bv = *(const float4*)&bias[d4 * 4];
            a0 = fmaxf(a0 + bv.x, 0.f); a1 = fmaxf(a1 + bv.y, 0.f);
            a2 = fmaxf(a2 + bv.z, 0.f); a3 = fmaxf(a3 + bv.w, 0.f);
        }
        if constexpr (sizeof(OT) == 4) {
            *(float4*)&out[(size_t)n * 64 + d4 * 4] = make_float4(a0, a1, a2, a3);
        } else {
            ushort4 u;
            u.x = f2bf(a0); u.y = f2bf(a1); u.z = f2bf(a2); u.w = f2bf(a3);
            *(ushort4*)&out[(size_t)n * 64 + d4 * 4] = u;
        }
    }
}

// ---- Linear: Y[n] = A[n] @ W^T (+bias)(relu). IT/OT: float or ushort(bf16)

template<typename IT, typename OT, int IN, int OUT, int NB_, bool RELU>
__global__ __launch_bounds__(256) void linear_kernel(
    const IT* __restrict__ A, const float* __restrict__ W,
    const float* __restrict__ bias, OT* __restrict__ Y, int N)
{
    constexpr int INP = IN + 4;
    constexpr int OT_ = OUT / 4;
    constexpr int NPT = (NB_ * OT_) / 256;
    __shared__ float Wl[IN][OUT];
    __shared__ float S[NB_][INP];
    int tid = threadIdx.x;
    for (int i = tid; i < IN * OUT; i += 256) {
        int k = i / OUT, o = i % OUT;
        Wl[k][o] = W[o * IN + k];
    }
    int n0 = blockIdx.x * NB_;
    for (int i = tid; i < NB_ * IN / 4; i += 256) {
        int idx = i * 4;
        int node = idx / IN, k = idx % IN;
        int gn = n0 + node;
        float4 v = make_float4(0.f, 0.f, 0.f, 0.f);
        if (gn < N) {
            if constexpr (sizeof(IT) == 4) {
                v = *(const float4*)&A[(size_t)gn * IN + k];
            } else {
                ushort4 u = *(const ushort4*)&A[(size_t)gn * IN + k];
                v = make_float4(bf2f(u.x), bf2f(u.y), bf2f(u.z), bf2f(u.w));
            }
        }
        *(float4*)&S[node][k] = v;
    }
    __syncthreads();
    int ot = (tid % OT_) * 4;
    int nt = (tid / OT_) * NPT;
    float acc[NPT][4];
    #pragma unroll
    for (int i = 0; i < NPT; ++i)
        acc[i][0] = acc[i][1] = acc[i][2] = acc[i][3] = 0.f;
    #pragma unroll 4
    for (int k = 0; k < IN; ++k) {
        float4 wv = *(const float4*)&Wl[k][ot];
        #pragma unroll
        for (int i = 0; i < NPT; ++i) {
            float a = S[nt + i][k];
            acc[i][0] += a * wv.x; acc[i][1] += a * wv.y;
            acc[i][2] += a * wv.z; acc[i][3] += a * wv.w;
        }
    }
    float4 bv = make_float4(0.f, 0.f, 0.f, 0.f);
    if (bias) bv = *(const float4*)&bias[ot];
    #pragma unroll
    for (int i = 0; i < NPT; ++i) {
        int gn = n0 + nt + i;
        if (gn < N) {
            float r0 = acc[i][0] + bv.x, r1 = acc[i][1] + bv.y;
            float r2 = acc[i][2] + bv.z, r3 = acc[i][3] + bv.w;
            if (RELU) {
                r0 = fmaxf(r0, 0.f); r1 = fmaxf(r1, 0.f);
                r2 = fmaxf(r2, 0.f); r3 = fmaxf(r3, 0.f);
            }
            if constexpr (sizeof(OT) == 4) {
                *(float4*)&Y[(size_t)gn * OUT + ot] =
                    make_float4(r0, r1, r2, r3);
            } else {
                ushort4 u;
                u.x = f2bf(r0); u.y = f2bf(r1); u.z = f2bf(r2); u.w = f2bf(r3);
                *(ushort4*)&Y[(size_t)gn * OUT + ot] = u;
            }
        }
    }
}

// ---- pool + FC ------------------------------------------------------------

__device__ inline int lower_bound_i(const int* a, int n, int v) {
    int lo = 0, hi = n;
    while (lo < hi) {
        int mid = (lo + hi) >> 1;
        if (a[mid] < v) lo = mid + 1; else hi = mid;
    }
    return lo;
}

__global__ __launch_bounds__(256) void pool_fc_kernel(
    const unsigned short* __restrict__ h3, const int* __restrict__ batch,
    const float* __restrict__ Wfc, const float* __restrict__ bfc,
    float* __restrict__ out, int N)
{
    int g = blockIdx.x;
    int tid = threadIdx.x;
    int w = tid >> 6, lane = tid & 63;
    int lo = lower_bound_i(batch, N, g);
    int hi = lower_bound_i(batch, N, g + 1);
    float sum = 0.f;
    for (int i = lo + w; i < hi; i += 4)
        sum += bf2f(h3[(size_t)i * 64 + lane]);
    __shared__ float P[4][64];
    P[w][lane] = sum;
    __syncthreads();
    if (w == 0) {
        float s = P[0][lane] + P[1][lane] + P[2][lane] + P[3][lane];
        float cnt = (float)((hi - lo) > 0 ? (hi - lo) : 1);
        P[0][lane] = s / cnt;
    }
    __syncthreads();
    if (tid < 11) {
        float s = bfc[tid];
        const float* wr = &Wfc[tid * 64];
        #pragma unroll 8
        for (int k = 0; k < 64; ++k) s += P[0][k] * wr[k];
        out[g * 11 + tid] = s;
    }
}

// ---------------------------------------------------------------------------

extern "C" void kernel_launch(void* const* d_in, const int* in_sizes, int n_in,
                              void* d_out, int out_size, void* d_ws, size_t ws_size,
                              hipStream_t stream) {
    const float* x    = (const float*)d_in[0];
    const int*   ei   = (const int*)d_in[1];
    const int*   batch= (const int*)d_in[2];
    const float* W1   = (const float*)d_in[3];
    const float* b1   = (const float*)d_in[4];
    const float* W2   = (const float*)d_in[5];
    const float* b2   = (const float*)d_in[6];
    const float* W3   = (const float*)d_in[7];
    const float* b3   = (const float*)d_in[8];
    const float* Wfc  = (const float*)d_in[9];
    const float* bfc  = (const float*)d_in[10];
    float* out = (float*)d_out;

    const int N = in_sizes[2];
    const int E = in_sizes[1] / 2;
    const int G = out_size / 11;
    const int* src = ei;
    const int* dst = ei + E;
    const int NB = (N + RB - 1) / RB;      // buckets
    const int NT = NB * NBLK;              // count entries
    const int SB = (NT + SCBS - 1) / SCBS; // scan chunks

    // workspace (all bf16 tables):
    //   B1 64N (h1 -> t3) | B2 64N (buf2 -> h3) | B3 128N (h2) | XB 16N (xb)
    //   then ints: pairs E | eidx E | rowstart N+1 | cnt NT | ofs NT | part
    unsigned short* B1 = (unsigned short*)d_ws;
    unsigned short* B2 = B1 + (size_t)64 * N;
    unsigned short* B3 = B2 + (size_t)64 * N;
    unsigned short* XB = B3 + (size_t)128 * N;
    int* pairs    = (int*)(XB + (size_t)16 * N);
    int* eidx     = pairs + E;
    int* rowstart = eidx + E;
    int* cnt      = rowstart + (N + 1);
    int* ofs      = cnt + NT;
    int* part     = ofs + NT;

    unsigned short* h1   = B1;
    unsigned short* buf2 = B2;
    unsigned short* h2   = B3;
    unsigned short* t3   = B1;   // h1 dead after gather2
    unsigned short* h3   = B2;   // buf2 dead after lin2
    unsigned short* xb   = XB;

    // ---- build: bucket-grouped pairs, then per-bucket CSR ----
    count_kernel<<<NBLK, CFBS, 0, stream>>>(dst, cnt, E, NB);
    scan_k1<<<SB, SCBS, 0, stream>>>(cnt, ofs, part, NT);
    scan_k2<<<1, SCBS, 0, stream>>>(part, SB);
    scan_k3<<<SB, SCBS, 0, stream>>>(ofs, part, NT);
    fillp_kernel<<<NBLK, CFBS, 0, stream>>>(src, dst, ofs, pairs, E, NB);
    bucket_csr_kernel<<<NB, 512, 0, stream>>>(pairs, ofs, rowstart, eidx, N, E, NB);
    xprep_kernel<<<(N + 255) / 256, 256, 0, stream>>>(x, xb, N);

    // ---- layer 1: vectorized 9-dim gather + Lin 9->64 + relu ----
    node1v_kernel<<<(N + 3) / 4, 256, 0, stream>>>(
        xb, rowstart, eidx, W1, b1, h1, N);

    // ---- layer 2 ----
    gather64v_kernel<false, unsigned short><<<(N + 3) / 4, 256, 0, stream>>>(
        h1, rowstart, eidx, nullptr, buf2, N);
    linear_kernel<unsigned short, unsigned short, 64, 128, 32, true>
        <<<(N + 31) / 32, 256, 0, stream>>>(buf2, W2, b2, h2, N);

    // ---- layer 3 ----
    linear_kernel<unsigned short, unsigned short, 128, 64, 32, false>
        <<<(N + 31) / 32, 256, 0, stream>>>(h2, W3, nullptr, t3, N);
    gather64v_kernel<true, unsigned short><<<(N + 3) / 4, 256, 0, stream>>>(
        t3, rowstart, eidx, b3, h3, N);

    // ---- pool + FC ----
    pool_fc_kernel<<<G, 256, 0, stream>>>(h3, batch, Wfc, bfc, out, N);
}

// Round 6
// 241.604 us; speedup vs baseline: 6.8781x; 1.4264x over previous
//
#include <hip/hip_runtime.h>
#include <hip/hip_bf16.h>

// ---------------------------------------------------------------------------
// GIN (3 layers, eps=0) + global mean pool + FC.
//
// Lessons: r1 global f32 atomics = 64B write-through; r2 per-node CSR fill =
//   105MB dirty lines; r3 block-per-bucket agg = latency collapse; r4/r5
//   wave-per-node vectorized gathers work; r5 linears were LDS-read-bound
//   (73us each, occupancy 28%).
// r6: linears on MFMA (16x16x32 bf16). Wave = 16-node strip; A-frags direct
//   from global bf16 table; W staged bf16 in LDS with +8-ushort row pad
//   (144B stride -> 2-way bank alias = free). Everything else unchanged.
// ---------------------------------------------------------------------------

#define NBLK 256      // blocks for count/fill
#define CFBS 512      // threads for count/fill
#define RB   128      // nodes per bucket
#define NBMAX 1024    // max buckets (N <= 131072)
#define SCBS 1024     // scan chunk

__device__ inline float bf2f(unsigned short u) {
    return __uint_as_float((unsigned)u << 16);
}
__device__ inline unsigned short f2bf(float f) {
    unsigned x = __float_as_uint(f);
    return (unsigned short)((x + 0x7FFFu + ((x >> 16) & 1u)) >> 16);  // RNE
}
__device__ inline float lo16(unsigned u) { return __uint_as_float(u << 16); }
__device__ inline float hi16(unsigned u) { return __uint_as_float(u & 0xFFFF0000u); }

// ---- bucket build ---------------------------------------------------------

__global__ __launch_bounds__(CFBS) void count_kernel(
    const int* __restrict__ dst, int* __restrict__ cnt, int E, int NB)
{
    __shared__ int hist[NBMAX];
    int tid = threadIdx.x;
    for (int i = tid; i < NBMAX; i += CFBS) hist[i] = 0;
    __syncthreads();
    for (int e = blockIdx.x * CFBS + tid; e < E; e += NBLK * CFBS)
        atomicAdd(&hist[dst[e] >> 7], 1);
    __syncthreads();
    for (int b = tid; b < NB; b += CFBS)
        cnt[b * NBLK + blockIdx.x] = hist[b];
}

__global__ __launch_bounds__(SCBS) void scan_k1(
    const int* __restrict__ cnt, int* __restrict__ ofs,
    int* __restrict__ part, int NT)
{
    __shared__ int tmp[SCBS];
    int i = blockIdx.x * SCBS + threadIdx.x;
    int v = (i < NT) ? cnt[i] : 0;
    tmp[threadIdx.x] = v;
    __syncthreads();
    for (int off = 1; off < SCBS; off <<= 1) {
        int t = (threadIdx.x >= off) ? tmp[threadIdx.x - off] : 0;
        __syncthreads();
        tmp[threadIdx.x] += t;
        __syncthreads();
    }
    if (i < NT) ofs[i] = tmp[threadIdx.x] - v;   // exclusive within chunk
    if (threadIdx.x == SCBS - 1) part[blockIdx.x] = tmp[threadIdx.x];
}

__global__ __launch_bounds__(SCBS) void scan_k2(int* __restrict__ part, int B)
{
    __shared__ int tmp[SCBS];
    int v = (threadIdx.x < B) ? part[threadIdx.x] : 0;
    tmp[threadIdx.x] = v;
    __syncthreads();
    for (int off = 1; off < SCBS; off <<= 1) {
        int t = (threadIdx.x >= off) ? tmp[threadIdx.x - off] : 0;
        __syncthreads();
        tmp[threadIdx.x] += t;
        __syncthreads();
    }
    if (threadIdx.x < B) part[threadIdx.x] = tmp[threadIdx.x] - v;
}

__global__ __launch_bounds__(SCBS) void scan_k3(
    int* __restrict__ ofs, const int* __restrict__ part, int NT)
{
    int i = blockIdx.x * SCBS + threadIdx.x;
    if (i < NT) ofs[i] += part[blockIdx.x];
}

__global__ __launch_bounds__(CFBS) void fillp_kernel(
    const int* __restrict__ src, const int* __restrict__ dst,
    const int* __restrict__ ofs, int* __restrict__ pairs, int E, int NB)
{
    __shared__ int cur[NBMAX];
    int tid = threadIdx.x;
    for (int b = tid; b < NB; b += CFBS)
        cur[b] = ofs[b * NBLK + blockIdx.x];
    __syncthreads();
    for (int e = blockIdx.x * CFBS + tid; e < E; e += NBLK * CFBS) {
        int d = dst[e];
        int b = d >> 7, dl = d & 127;
        int pos = atomicAdd(&cur[b], 1);
        pairs[pos] = (dl << 20) | src[e];
    }
}

// per-bucket CSR finalize: writes land in bucket-local contiguous windows
__global__ __launch_bounds__(512) void bucket_csr_kernel(
    const int* __restrict__ pairs, const int* __restrict__ ofs,
    int* __restrict__ rowstart, int* __restrict__ eidx, int N, int E, int NB)
{
    __shared__ int deg[RB], pfx[RB], cur[RB];
    int tid = threadIdx.x;
    int b = blockIdx.x, n0 = b << 7;
    int e0 = ofs[b * NBLK];
    int e1 = (b + 1 < NB) ? ofs[(b + 1) * NBLK] : E;
    if (tid < RB) deg[tid] = 0;
    __syncthreads();
    for (int e = e0 + tid; e < e1; e += 512)
        atomicAdd(&deg[pairs[e] >> 20], 1);
    __syncthreads();
    if (tid < RB) pfx[tid] = deg[tid];
    __syncthreads();
    for (int off = 1; off < RB; off <<= 1) {
        int t = (tid < RB && tid >= off) ? pfx[tid - off] : 0;
        __syncthreads();
        if (tid < RB) pfx[tid] += t;
        __syncthreads();
    }
    if (tid < RB) {
        int ex = pfx[tid] - deg[tid];     // exclusive
        cur[tid] = ex;
        int n = n0 + tid;
        if (n < N) rowstart[n] = e0 + ex;
    }
    if (b == NB - 1 && tid == 0) rowstart[N] = E;
    __syncthreads();
    for (int e = e0 + tid; e < e1; e += 512) {
        int p = pairs[e];
        int pos = e0 + atomicAdd(&cur[p >> 20], 1);
        eidx[pos] = p & 0xFFFFF;
    }
}

// ---- x prep: xb[N][16] bf16 (pad 9->16) ----------------------------------

__global__ __launch_bounds__(256) void xprep_kernel(
    const float* __restrict__ x, unsigned short* __restrict__ xb, int N)
{
    int n = blockIdx.x * 256 + threadIdx.x;
    if (n >= N) return;
    unsigned short r[16];
    #pragma unroll
    for (int k = 0; k < 9; ++k) r[k] = f2bf(x[(size_t)n * 9 + k]);
    #pragma unroll
    for (int k = 9; k < 16; ++k) r[k] = 0;
    uint4 u0, u1;
    u0.x = r[0] | ((unsigned)r[1] << 16);  u0.y = r[2] | ((unsigned)r[3] << 16);
    u0.z = r[4] | ((unsigned)r[5] << 16);  u0.w = r[6] | ((unsigned)r[7] << 16);
    u1.x = r[8] | ((unsigned)r[9] << 16);  u1.y = 0; u1.z = 0; u1.w = 0;
    *(uint4*)&xb[(size_t)n * 16]     = u0;
    *(uint4*)&xb[(size_t)n * 16 + 8] = u1;
}

// ---- layer 1: 9-dim gather (16 edge-grp x 4 dim-grp) + Lin 9->64 + relu --

__global__ __launch_bounds__(256) void node1v_kernel(
    const unsigned short* __restrict__ xb, const int* __restrict__ rs,
    const int* __restrict__ eidx, const float* __restrict__ W1,
    const float* __restrict__ b1, unsigned short* __restrict__ h1, int N)
{
    __shared__ float Wl[576];
    __shared__ float bl[64];
    for (int i = threadIdx.x; i < 576; i += 256) Wl[i] = W1[i];
    if (threadIdx.x < 64) bl[threadIdx.x] = b1[threadIdx.x];
    __syncthreads();
    int n = blockIdx.x * 4 + (threadIdx.x >> 6);
    if (n >= N) return;
    int lane = threadIdx.x & 63;
    int g  = lane >> 2;     // edge group 0..15
    int d4 = lane & 3;      // dims 4*d4 .. 4*d4+3
    float a0 = 0.f, a1 = 0.f, a2 = 0.f, a3 = 0.f;
    if (g == 0) {           // self term, added once by lanes 0..3
        uint2 u = *(const uint2*)&xb[(size_t)n * 16 + d4 * 4];
        a0 += lo16(u.x); a1 += hi16(u.x); a2 += lo16(u.y); a3 += hi16(u.y);
    }
    int e0 = rs[n], e1 = rs[n + 1];
    for (int e = e0; e < e1; e += 16) {
        int idx = e + g;
        if (idx < e1) {
            int s = eidx[idx];
            uint2 u = *(const uint2*)&xb[(size_t)s * 16 + d4 * 4];
            a0 += lo16(u.x); a1 += hi16(u.x); a2 += lo16(u.y); a3 += hi16(u.y);
        }
    }
    #pragma unroll
    for (int m = 4; m < 64; m <<= 1) {
        a0 += __shfl_xor(a0, m); a1 += __shfl_xor(a1, m);
        a2 += __shfl_xor(a2, m); a3 += __shfl_xor(a3, m);
    }
    // dim k total lives in lane (k>>2), register a[k&3]
    float xv[9];
    xv[0] = __shfl(a0, 0); xv[1] = __shfl(a1, 0); xv[2] = __shfl(a2, 0);
    xv[3] = __shfl(a3, 0); xv[4] = __shfl(a0, 1); xv[5] = __shfl(a1, 1);
    xv[6] = __shfl(a2, 1); xv[7] = __shfl(a3, 1); xv[8] = __shfl(a0, 2);
    float s = bl[lane];
    const float* wr = &Wl[lane * 9];
    #pragma unroll
    for (int k = 0; k < 9; ++k) s += xv[k] * wr[k];
    h1[(size_t)n * 64 + lane] = f2bf(fmaxf(s, 0.f));
}

// ---- 64-dim gather: 4 edge-grp x 16 dim-grp, uint2 loads, unroll 2 -------

template<bool BIAS_RELU, typename OT>
__global__ __launch_bounds__(256) void gather64v_kernel(
    const unsigned short* __restrict__ feat, const int* __restrict__ rs,
    const int* __restrict__ eidx, const float* __restrict__ bias,
    OT* __restrict__ out, int N)
{
    int n = blockIdx.x * 4 + (threadIdx.x >> 6);
    if (n >= N) return;
    int lane = threadIdx.x & 63;
    int g  = lane >> 4;     // edge group 0..3
    int d4 = lane & 15;     // dims 4*d4 .. 4*d4+3
    float a0 = 0.f, a1 = 0.f, a2 = 0.f, a3 = 0.f;
    if (g == 0) {           // self term
        uint2 u = *(const uint2*)&feat[(size_t)n * 64 + d4 * 4];
        a0 += lo16(u.x); a1 += hi16(u.x); a2 += lo16(u.y); a3 += hi16(u.y);
    }
    int e0 = rs[n], e1 = rs[n + 1];
    int e = e0;
    for (; e + 8 <= e1; e += 8) {
        int sA = eidx[e + g];
        int sB = eidx[e + 4 + g];
        uint2 uA = *(const uint2*)&feat[(size_t)sA * 64 + d4 * 4];
        uint2 uB = *(const uint2*)&feat[(size_t)sB * 64 + d4 * 4];
        a0 += lo16(uA.x); a1 += hi16(uA.x); a2 += lo16(uA.y); a3 += hi16(uA.y);
        a0 += lo16(uB.x); a1 += hi16(uB.x); a2 += lo16(uB.y); a3 += hi16(uB.y);
    }
    for (; e < e1; e += 4) {
        int idx = e + g;
        if (idx < e1) {
            int s = eidx[idx];
            uint2 u = *(const uint2*)&feat[(size_t)s * 64 + d4 * 4];
            a0 += lo16(u.x); a1 += hi16(u.x); a2 += lo16(u.y); a3 += hi16(u.y);
        }
    }
    a0 += __shfl_xor(a0, 16); a1 += __shfl_xor(a1, 16);
    a2 += __shfl_xor(a2, 16); a3 += __shfl_xor(a3, 16);
    a0 += __shfl_xor(a0, 32); a1 += __shfl_xor(a1, 32);
    a2 += __shfl_xor(a2, 32); a3 += __shfl_xor(a3, 32);
    if (g == 0) {
        if (BIAS_RELU) {
            float4 bv = *(const float4*)&bias[d4 * 4];
            a0 = fmaxf(a0 + bv.x, 0.f); a1 = fmaxf(a1 + bv.y, 0.f);
            a2 = fmaxf(a2 + bv.z, 0.f); a3 = fmaxf(a3 + bv.w, 0.f);
        }
        if constexpr (sizeof(OT) == 4) {
            *(float4*)&out[(size_t)n * 64 + d4 * 4] = make_float4(a0, a1, a2, a3);
        } else {
            ushort4 u;
            u.x = f2bf(a0); u.y = f2bf(a1); u.z = f2bf(a2); u.w = f2bf(a3);
            *(ushort4*)&out[(size_t)n * 64 + d4 * 4] = u;
        }
    }
}

// ---- MFMA linear: Y[n,:OUT] = relu?(A[n,:IN] @ W^T + bias), bf16 tables ---
// Block: 64 nodes, 4 waves; wave = 16-node strip, all OUT cols.
// A-frag (16x16x32): lane l -> row l&15, k = (l>>4)*8 + j (16B global load).
// B-frag: lane l -> col l&15, same k slice, from LDS W[o][k] bf16,
//   row stride IN+8 ushorts (144B/272B) -> 2-way bank alias only (free).
// D: col = lane&15, row = (lane>>4)*4 + reg  [m89-verified].

template<int IN, int OUT, bool RELU>
__global__ __launch_bounds__(256) void linear_mfma_kernel(
    const unsigned short* __restrict__ A, const float* __restrict__ W,
    const float* __restrict__ bias, unsigned short* __restrict__ Y, int N)
{
    using s8v = __attribute__((ext_vector_type(8))) short;
    using f4v = __attribute__((ext_vector_type(4))) float;
    constexpr int KT = IN / 32;       // K-steps
    constexpr int CT = OUT / 16;      // col tiles
    constexpr int INP = IN + 8;       // padded row stride (ushorts)
    __shared__ __align__(16) unsigned short Wb[OUT * INP];
    __shared__ float bl[OUT];
    int tid = threadIdx.x;
    for (int i = tid; i < OUT * IN; i += 256) {
        int o = i / IN, k = i % IN;
        Wb[o * INP + k] = f2bf(W[i]);
    }
    for (int i = tid; i < OUT; i += 256) bl[i] = bias ? bias[i] : 0.f;
    __syncthreads();

    int w = tid >> 6, lane = tid & 63;
    int n0 = blockIdx.x * 64 + w * 16;
    int hl = lane >> 4;               // k-slice 0..3
    int ll = lane & 15;               // row (A) / col (B)

    int an = n0 + ll;
    if (an >= N) an = N - 1;          // clamp: garbage rows never written
    const unsigned short* arow = &A[(size_t)an * IN + hl * 8];
    s8v a[KT];
    #pragma unroll
    for (int ks = 0; ks < KT; ++ks) a[ks] = *(const s8v*)&arow[ks * 32];

    f4v acc[CT];
    #pragma unroll
    for (int c = 0; c < CT; ++c) acc[c] = (f4v){0.f, 0.f, 0.f, 0.f};
    #pragma unroll
    for (int c = 0; c < CT; ++c) {
        const unsigned short* wrow = &Wb[(c * 16 + ll) * INP + hl * 8];
        #pragma unroll
        for (int ks = 0; ks < KT; ++ks) {
            s8v b = *(const s8v*)&wrow[ks * 32];
            acc[c] = __builtin_amdgcn_mfma_f32_16x16x32_bf16(a[ks], b, acc[c], 0, 0, 0);
        }
    }
    #pragma unroll
    for (int c = 0; c < CT; ++c) {
        int col = c * 16 + ll;
        float bv = bl[col];
        #pragma unroll
        for (int r = 0; r < 4; ++r) {
            int gn = n0 + hl * 4 + r;
            if (gn < N) {
                float v = acc[c][r] + bv;
                if (RELU) v = fmaxf(v, 0.f);
                Y[(size_t)gn * OUT + col] = f2bf(v);
            }
        }
    }
}

// ---- pool + FC ------------------------------------------------------------

__device__ inline int lower_bound_i(const int* a, int n, int v) {
    int lo = 0, hi = n;
    while (lo < hi) {
        int mid = (lo + hi) >> 1;
        if (a[mid] < v) lo = mid + 1; else hi = mid;
    }
    return lo;
}

__global__ __launch_bounds__(256) void pool_fc_kernel(
    const unsigned short* __restrict__ h3, const int* __restrict__ batch,
    const float* __restrict__ Wfc, const float* __restrict__ bfc,
    float* __restrict__ out, int N)
{
    int g = blockIdx.x;
    int tid = threadIdx.x;
    int w = tid >> 6, lane = tid & 63;
    int lo = lower_bound_i(batch, N, g);
    int hi = lower_bound_i(batch, N, g + 1);
    float sum = 0.f;
    for (int i = lo + w; i < hi; i += 4)
        sum += bf2f(h3[(size_t)i * 64 + lane]);
    __shared__ float P[4][64];
    P[w][lane] = sum;
    __syncthreads();
    if (w == 0) {
        float s = P[0][lane] + P[1][lane] + P[2][lane] + P[3][lane];
        float cnt = (float)((hi - lo) > 0 ? (hi - lo) : 1);
        P[0][lane] = s / cnt;
    }
    __syncthreads();
    if (tid < 11) {
        float s = bfc[tid];
        const float* wr = &Wfc[tid * 64];
        #pragma unroll 8
        for (int k = 0; k < 64; ++k) s += P[0][k] * wr[k];
        out[g * 11 + tid] = s;
    }
}

// ---------------------------------------------------------------------------

extern "C" void kernel_launch(void* const* d_in, const int* in_sizes, int n_in,
                              void* d_out, int out_size, void* d_ws, size_t ws_size,
                              hipStream_t stream) {
    const float* x    = (const float*)d_in[0];
    const int*   ei   = (const int*)d_in[1];
    const int*   batch= (const int*)d_in[2];
    const float* W1   = (const float*)d_in[3];
    const float* b1   = (const float*)d_in[4];
    const float* W2   = (const float*)d_in[5];
    const float* b2   = (const float*)d_in[6];
    const float* W3   = (const float*)d_in[7];
    const float* b3   = (const float*)d_in[8];
    const float* Wfc  = (const float*)d_in[9];
    const float* bfc  = (const float*)d_in[10];
    float* out = (float*)d_out;

    const int N = in_sizes[2];
    const int E = in_sizes[1] / 2;
    const int G = out_size / 11;
    const int* src = ei;
    const int* dst = ei + E;
    const int NB = (N + RB - 1) / RB;      // buckets
    const int NT = NB * NBLK;              // count entries
    const int SB = (NT + SCBS - 1) / SCBS; // scan chunks

    // workspace (all bf16 tables):
    //   B1 64N (h1 -> t3) | B2 64N (buf2 -> h3) | B3 128N (h2) | XB 16N (xb)
    //   then ints: pairs E | eidx E | rowstart N+1 | cnt NT | ofs NT | part
    unsigned short* B1 = (unsigned short*)d_ws;
    unsigned short* B2 = B1 + (size_t)64 * N;
    unsigned short* B3 = B2 + (size_t)64 * N;
    unsigned short* XB = B3 + (size_t)128 * N;
    int* pairs    = (int*)(XB + (size_t)16 * N);
    int* eidx     = pairs + E;
    int* rowstart = eidx + E;
    int* cnt      = rowstart + (N + 1);
    int* ofs      = cnt + NT;
    int* part     = ofs + NT;

    unsigned short* h1   = B1;
    unsigned short* buf2 = B2;
    unsigned short* h2   = B3;
    unsigned short* t3   = B1;   // h1 dead after gather2
    unsigned short* h3   = B2;   // buf2 dead after lin2
    unsigned short* xb   = XB;

    // ---- build: bucket-grouped pairs, then per-bucket CSR ----
    count_kernel<<<NBLK, CFBS, 0, stream>>>(dst, cnt, E, NB);
    scan_k1<<<SB, SCBS, 0, stream>>>(cnt, ofs, part, NT);
    scan_k2<<<1, SCBS, 0, stream>>>(part, SB);
    scan_k3<<<SB, SCBS, 0, stream>>>(ofs, part, NT);
    fillp_kernel<<<NBLK, CFBS, 0, stream>>>(src, dst, ofs, pairs, E, NB);
    bucket_csr_kernel<<<NB, 512, 0, stream>>>(pairs, ofs, rowstart, eidx, N, E, NB);
    xprep_kernel<<<(N + 255) / 256, 256, 0, stream>>>(x, xb, N);

    // ---- layer 1: vectorized 9-dim gather + Lin 9->64 + relu ----
    node1v_kernel<<<(N + 3) / 4, 256, 0, stream>>>(
        xb, rowstart, eidx, W1, b1, h1, N);

    // ---- layer 2 ----
    gather64v_kernel<false, unsigned short><<<(N + 3) / 4, 256, 0, stream>>>(
        h1, rowstart, eidx, nullptr, buf2, N);
    linear_mfma_kernel<64, 128, true><<<(N + 63) / 64, 256, 0, stream>>>(
        buf2, W2, b2, h2, N);

    // ---- layer 3 ----
    linear_mfma_kernel<128, 64, false><<<(N + 63) / 64, 256, 0, stream>>>(
        h2, W3, nullptr, t3, N);
    gather64v_kernel<true, unsigned short><<<(N + 3) / 4, 256, 0, stream>>>(
        t3, rowstart, eidx, b3, h3, N);

    // ---- pool + FC ----
    pool_fc_kernel<<<G, 256, 0, stream>>>(h3, batch, Wfc, bfc, out, N);
}

// Round 8
// 233.351 us; speedup vs baseline: 7.1214x; 1.0354x over previous
//
#include <hip/hip_runtime.h>
#include <hip/hip_bf16.h>

// ---------------------------------------------------------------------------
// GIN (3 layers, eps=0) + global mean pool + FC.
//
// Lessons: r1 global f32 atomics = 64B write-through; r2 per-node CSR fill =
//   105MB dirty lines; r3 block-per-bucket agg = latency collapse; r5 linears
//   LDS-read-bound -> r6 MFMA linears; r6 gathers latency-bound (2 loads in
//   flight); r7 added eidx-preload + shfl-broadcast BUT put __shfl inside a
//   divergent guard -> ds_bpermute sources inactive lanes -> garbage (absmax
//   19). r8: shfl hoisted to uniform flow with clamped source index; only the
//   load/accumulate stays guarded.
// ---------------------------------------------------------------------------

#define NBLK 256      // blocks for count/fill
#define CFBS 512      // threads for count/fill
#define RB   128      // nodes per bucket
#define NBMAX 1024    // max buckets (N <= 131072)
#define SCBS 1024     // scan chunk

__device__ inline float bf2f(unsigned short u) {
    return __uint_as_float((unsigned)u << 16);
}
__device__ inline unsigned short f2bf(float f) {
    unsigned x = __float_as_uint(f);
    return (unsigned short)((x + 0x7FFFu + ((x >> 16) & 1u)) >> 16);  // RNE
}
__device__ inline float lo16(unsigned u) { return __uint_as_float(u << 16); }
__device__ inline float hi16(unsigned u) { return __uint_as_float(u & 0xFFFF0000u); }

// ---- bucket build ---------------------------------------------------------

__global__ __launch_bounds__(CFBS) void count_kernel(
    const int* __restrict__ dst, int* __restrict__ cnt, int E, int NB)
{
    __shared__ int hist[NBMAX];
    int tid = threadIdx.x;
    for (int i = tid; i < NBMAX; i += CFBS) hist[i] = 0;
    __syncthreads();
    for (int e = blockIdx.x * CFBS + tid; e < E; e += NBLK * CFBS)
        atomicAdd(&hist[dst[e] >> 7], 1);
    __syncthreads();
    for (int b = tid; b < NB; b += CFBS)
        cnt[b * NBLK + blockIdx.x] = hist[b];
}

__global__ __launch_bounds__(SCBS) void scan_k1(
    const int* __restrict__ cnt, int* __restrict__ ofs,
    int* __restrict__ part, int NT)
{
    __shared__ int tmp[SCBS];
    int i = blockIdx.x * SCBS + threadIdx.x;
    int v = (i < NT) ? cnt[i] : 0;
    tmp[threadIdx.x] = v;
    __syncthreads();
    for (int off = 1; off < SCBS; off <<= 1) {
        int t = (threadIdx.x >= off) ? tmp[threadIdx.x - off] : 0;
        __syncthreads();
        tmp[threadIdx.x] += t;
        __syncthreads();
    }
    if (i < NT) ofs[i] = tmp[threadIdx.x] - v;   // exclusive within chunk
    if (threadIdx.x == SCBS - 1) part[blockIdx.x] = tmp[threadIdx.x];
}

__global__ __launch_bounds__(SCBS) void scan_k2(int* __restrict__ part, int B)
{
    __shared__ int tmp[SCBS];
    int v = (threadIdx.x < B) ? part[threadIdx.x] : 0;
    tmp[threadIdx.x] = v;
    __syncthreads();
    for (int off = 1; off < SCBS; off <<= 1) {
        int t = (threadIdx.x >= off) ? tmp[threadIdx.x - off] : 0;
        __syncthreads();
        tmp[threadIdx.x] += t;
        __syncthreads();
    }
    if (threadIdx.x < B) part[threadIdx.x] = tmp[threadIdx.x] - v;
}

__global__ __launch_bounds__(SCBS) void scan_k3(
    int* __restrict__ ofs, const int* __restrict__ part, int NT)
{
    int i = blockIdx.x * SCBS + threadIdx.x;
    if (i < NT) ofs[i] += part[blockIdx.x];
}

__global__ __launch_bounds__(CFBS) void fillp_kernel(
    const int* __restrict__ src, const int* __restrict__ dst,
    const int* __restrict__ ofs, int* __restrict__ pairs, int E, int NB)
{
    __shared__ int cur[NBMAX];
    int tid = threadIdx.x;
    for (int b = tid; b < NB; b += CFBS)
        cur[b] = ofs[b * NBLK + blockIdx.x];
    __syncthreads();
    for (int e = blockIdx.x * CFBS + tid; e < E; e += NBLK * CFBS) {
        int d = dst[e];
        int b = d >> 7, dl = d & 127;
        int pos = atomicAdd(&cur[b], 1);
        pairs[pos] = (dl << 20) | src[e];
    }
}

// per-bucket CSR finalize: writes land in bucket-local contiguous windows
__global__ __launch_bounds__(512) void bucket_csr_kernel(
    const int* __restrict__ pairs, const int* __restrict__ ofs,
    int* __restrict__ rowstart, int* __restrict__ eidx, int N, int E, int NB)
{
    __shared__ int deg[RB], pfx[RB], cur[RB];
    int tid = threadIdx.x;
    int b = blockIdx.x, n0 = b << 7;
    int e0 = ofs[b * NBLK];
    int e1 = (b + 1 < NB) ? ofs[(b + 1) * NBLK] : E;
    if (tid < RB) deg[tid] = 0;
    __syncthreads();
    for (int e = e0 + tid; e < e1; e += 512)
        atomicAdd(&deg[pairs[e] >> 20], 1);
    __syncthreads();
    if (tid < RB) pfx[tid] = deg[tid];
    __syncthreads();
    for (int off = 1; off < RB; off <<= 1) {
        int t = (tid < RB && tid >= off) ? pfx[tid - off] : 0;
        __syncthreads();
        if (tid < RB) pfx[tid] += t;
        __syncthreads();
    }
    if (tid < RB) {
        int ex = pfx[tid] - deg[tid];     // exclusive
        cur[tid] = ex;
        int n = n0 + tid;
        if (n < N) rowstart[n] = e0 + ex;
    }
    if (b == NB - 1 && tid == 0) rowstart[N] = E;
    __syncthreads();
    for (int e = e0 + tid; e < e1; e += 512) {
        int p = pairs[e];
        int pos = e0 + atomicAdd(&cur[p >> 20], 1);
        eidx[pos] = p & 0xFFFFF;
    }
}

// ---- x prep: xb[N][16] bf16 (pad 9->16) ----------------------------------

__global__ __launch_bounds__(256) void xprep_kernel(
    const float* __restrict__ x, unsigned short* __restrict__ xb, int N)
{
    int n = blockIdx.x * 256 + threadIdx.x;
    if (n >= N) return;
    unsigned short r[16];
    #pragma unroll
    for (int k = 0; k < 9; ++k) r[k] = f2bf(x[(size_t)n * 9 + k]);
    #pragma unroll
    for (int k = 9; k < 16; ++k) r[k] = 0;
    uint4 u0, u1;
    u0.x = r[0] | ((unsigned)r[1] << 16);  u0.y = r[2] | ((unsigned)r[3] << 16);
    u0.z = r[4] | ((unsigned)r[5] << 16);  u0.w = r[6] | ((unsigned)r[7] << 16);
    u1.x = r[8] | ((unsigned)r[9] << 16);  u1.y = 0; u1.z = 0; u1.w = 0;
    *(uint4*)&xb[(size_t)n * 16]     = u0;
    *(uint4*)&xb[(size_t)n * 16 + 8] = u1;
}

// ---- layer 1: 9-dim gather (16 edge-grp x 4 dim-grp) + Lin 9->64 + relu --
// eidx preloaded cooperatively; __shfl always in uniform flow (clamped src).

__global__ __launch_bounds__(256) void node1v_kernel(
    const unsigned short* __restrict__ xb, const int* __restrict__ rs,
    const int* __restrict__ eidx, const float* __restrict__ W1,
    const float* __restrict__ b1, unsigned short* __restrict__ h1, int N)
{
    __shared__ float Wl[576];
    __shared__ float bl[64];
    for (int i = threadIdx.x; i < 576; i += 256) Wl[i] = W1[i];
    if (threadIdx.x < 64) bl[threadIdx.x] = b1[threadIdx.x];
    __syncthreads();
    int n = blockIdx.x * 4 + (threadIdx.x >> 6);
    if (n >= N) return;
    int lane = threadIdx.x & 63;
    int g  = lane >> 2;     // edge group 0..15
    int d4 = lane & 3;      // dims 4*d4 .. 4*d4+3
    float a0 = 0.f, a1 = 0.f, a2 = 0.f, a3 = 0.f;
    if (g == 0) {           // self term, added once by lanes 0..3
        uint2 u = *(const uint2*)&xb[(size_t)n * 16 + d4 * 4];
        a0 += lo16(u.x); a1 += hi16(u.x); a2 += lo16(u.y); a3 += hi16(u.y);
    }
    int e0 = rs[n], e1 = rs[n + 1];
    int deg = e1 - e0;
    for (int w0 = 0; w0 < deg; w0 += 64) {
        int wd = min(deg - w0, 64);
        int sidx = (lane < wd) ? eidx[e0 + w0 + lane] : 0;
        int c = 0;
        for (; c + 32 <= wd; c += 32) {   // uniform flow, sources < wd
            int s0 = __shfl(sidx, c + g);
            int s1 = __shfl(sidx, c + 16 + g);
            uint2 u0 = *(const uint2*)&xb[(size_t)s0 * 16 + d4 * 4];
            uint2 u1 = *(const uint2*)&xb[(size_t)s1 * 16 + d4 * 4];
            a0 += lo16(u0.x) + lo16(u1.x); a1 += hi16(u0.x) + hi16(u1.x);
            a2 += lo16(u0.y) + lo16(u1.y); a3 += hi16(u0.y) + hi16(u1.y);
        }
        for (; c < wd; c += 16) {
            int idx = c + g;
            // shfl OUTSIDE the guard (uniform flow), clamped valid source;
            // ds_bpermute provides data only from ACTIVE lanes (r7 bug).
            int s = __shfl(sidx, idx < wd ? idx : 0);
            if (idx < wd) {
                uint2 u = *(const uint2*)&xb[(size_t)s * 16 + d4 * 4];
                a0 += lo16(u.x); a1 += hi16(u.x); a2 += lo16(u.y); a3 += hi16(u.y);
            }
        }
    }
    #pragma unroll
    for (int m = 4; m < 64; m <<= 1) {
        a0 += __shfl_xor(a0, m); a1 += __shfl_xor(a1, m);
        a2 += __shfl_xor(a2, m); a3 += __shfl_xor(a3, m);
    }
    // dim k total lives in lane (k>>2), register a[k&3]
    float xv[9];
    xv[0] = __shfl(a0, 0); xv[1] = __shfl(a1, 0); xv[2] = __shfl(a2, 0);
    xv[3] = __shfl(a3, 0); xv[4] = __shfl(a0, 1); xv[5] = __shfl(a1, 1);
    xv[6] = __shfl(a2, 1); xv[7] = __shfl(a3, 1); xv[8] = __shfl(a0, 2);
    float s = bl[lane];
    const float* wr = &Wl[lane * 9];
    #pragma unroll
    for (int k = 0; k < 9; ++k) s += xv[k] * wr[k];
    h1[(size_t)n * 64 + lane] = f2bf(fmaxf(s, 0.f));
}

// ---- 64-dim gather: 4 edge-grp x 16 dim-grp, eidx preload, 4 loads deep --

template<bool BIAS_RELU>
__global__ __launch_bounds__(256) void gather64v_kernel(
    const unsigned short* __restrict__ feat, const int* __restrict__ rs,
    const int* __restrict__ eidx, const float* __restrict__ bias,
    unsigned short* __restrict__ out, int N)
{
    int n = blockIdx.x * 4 + (threadIdx.x >> 6);
    if (n >= N) return;
    int lane = threadIdx.x & 63;
    int g  = lane >> 4;     // edge group 0..3
    int d4 = lane & 15;     // dims 4*d4 .. 4*d4+3
    float a0 = 0.f, a1 = 0.f, a2 = 0.f, a3 = 0.f;
    if (g == 0) {           // self term
        uint2 u = *(const uint2*)&feat[(size_t)n * 64 + d4 * 4];
        a0 += lo16(u.x); a1 += hi16(u.x); a2 += lo16(u.y); a3 += hi16(u.y);
    }
    int e0 = rs[n], e1 = rs[n + 1];
    int deg = e1 - e0;
    for (int w0 = 0; w0 < deg; w0 += 64) {
        int wd = min(deg - w0, 64);
        int sidx = (lane < wd) ? eidx[e0 + w0 + lane] : 0;
        int c = 0;
        for (; c + 16 <= wd; c += 16) {   // uniform flow, sources < wd
            int s0 = __shfl(sidx, c + g);
            int s1 = __shfl(sidx, c + 4 + g);
            int s2 = __shfl(sidx, c + 8 + g);
            int s3 = __shfl(sidx, c + 12 + g);
            uint2 u0 = *(const uint2*)&feat[(size_t)s0 * 64 + d4 * 4];
            uint2 u1 = *(const uint2*)&feat[(size_t)s1 * 64 + d4 * 4];
            uint2 u2 = *(const uint2*)&feat[(size_t)s2 * 64 + d4 * 4];
            uint2 u3 = *(const uint2*)&feat[(size_t)s3 * 64 + d4 * 4];
            a0 += (lo16(u0.x) + lo16(u1.x)) + (lo16(u2.x) + lo16(u3.x));
            a1 += (hi16(u0.x) + hi16(u1.x)) + (hi16(u2.x) + hi16(u3.x));
            a2 += (lo16(u0.y) + lo16(u1.y)) + (lo16(u2.y) + lo16(u3.y));
            a3 += (hi16(u0.y) + hi16(u1.y)) + (hi16(u2.y) + hi16(u3.y));
        }
        for (; c < wd; c += 4) {
            int idx = c + g;
            // shfl OUTSIDE the guard (uniform flow), clamped valid source
            int s = __shfl(sidx, idx < wd ? idx : 0);
            if (idx < wd) {
                uint2 u = *(const uint2*)&feat[(size_t)s * 64 + d4 * 4];
                a0 += lo16(u.x); a1 += hi16(u.x); a2 += lo16(u.y); a3 += hi16(u.y);
            }
        }
    }
    a0 += __shfl_xor(a0, 16); a1 += __shfl_xor(a1, 16);
    a2 += __shfl_xor(a2, 16); a3 += __shfl_xor(a3, 16);
    a0 += __shfl_xor(a0, 32); a1 += __shfl_xor(a1, 32);
    a2 += __shfl_xor(a2, 32); a3 += __shfl_xor(a3, 32);
    if (g == 0) {
        if (BIAS_RELU) {
            float4 bv = *(const float4*)&bias[d4 * 4];
            a0 = fmaxf(a0 + bv.x, 0.f); a1 = fmaxf(a1 + bv.y, 0.f);
            a2 = fmaxf(a2 + bv.z, 0.f); a3 = fmaxf(a3 + bv.w, 0.f);
        }
        ushort4 u;
        u.x = f2bf(a0); u.y = f2bf(a1); u.z = f2bf(a2); u.w = f2bf(a3);
        *(ushort4*)&out[(size_t)n * 64 + d4 * 4] = u;
    }
}

// ---- MFMA linear: Y[n,:OUT] = relu?(A[n,:IN] @ W^T + bias), bf16 tables ---

template<int IN, int OUT, bool RELU>
__global__ __launch_bounds__(256) void linear_mfma_kernel(
    const unsigned short* __restrict__ A, const float* __restrict__ W,
    const float* __restrict__ bias, unsigned short* __restrict__ Y, int N)
{
    using s8v = __attribute__((ext_vector_type(8))) short;
    using f4v = __attribute__((ext_vector_type(4))) float;
    constexpr int KT = IN / 32;       // K-steps
    constexpr int CT = OUT / 16;      // col tiles
    constexpr int INP = IN + 8;       // padded row stride (ushorts)
    __shared__ __align__(16) unsigned short Wb[OUT * INP];
    __shared__ float bl[OUT];
    int tid = threadIdx.x;
    for (int i = tid; i < OUT * IN; i += 256) {
        int o = i / IN, k = i % IN;
        Wb[o * INP + k] = f2bf(W[i]);
    }
    for (int i = tid; i < OUT; i += 256) bl[i] = bias ? bias[i] : 0.f;
    __syncthreads();

    int w = tid >> 6, lane = tid & 63;
    int n0 = blockIdx.x * 64 + w * 16;
    int hl = lane >> 4;               // k-slice 0..3
    int ll = lane & 15;               // row (A) / col (B)

    int an = n0 + ll;
    if (an >= N) an = N - 1;          // clamp: garbage rows never written
    const unsigned short* arow = &A[(size_t)an * IN + hl * 8];
    s8v a[KT];
    #pragma unroll
    for (int ks = 0; ks < KT; ++ks) a[ks] = *(const s8v*)&arow[ks * 32];

    f4v acc[CT];
    #pragma unroll
    for (int c = 0; c < CT; ++c) acc[c] = (f4v){0.f, 0.f, 0.f, 0.f};
    #pragma unroll
    for (int c = 0; c < CT; ++c) {
        const unsigned short* wrow = &Wb[(c * 16 + ll) * INP + hl * 8];
        #pragma unroll
        for (int ks = 0; ks < KT; ++ks) {
            s8v b = *(const s8v*)&wrow[ks * 32];
            acc[c] = __builtin_amdgcn_mfma_f32_16x16x32_bf16(a[ks], b, acc[c], 0, 0, 0);
        }
    }
    #pragma unroll
    for (int c = 0; c < CT; ++c) {
        int col = c * 16 + ll;
        float bv = bl[col];
        #pragma unroll
        for (int r = 0; r < 4; ++r) {
            int gn = n0 + hl * 4 + r;
            if (gn < N) {
                float v = acc[c][r] + bv;
                if (RELU) v = fmaxf(v, 0.f);
                Y[(size_t)gn * OUT + col] = f2bf(v);
            }
        }
    }
}

// ---- pool + FC ------------------------------------------------------------

__device__ inline int lower_bound_i(const int* a, int n, int v) {
    int lo = 0, hi = n;
    while (lo < hi) {
        int mid = (lo + hi) >> 1;
        if (a[mid] < v) lo = mid + 1; else hi = mid;
    }
    return lo;
}

__global__ __launch_bounds__(256) void pool_fc_kernel(
    const unsigned short* __restrict__ h3, const int* __restrict__ batch,
    const float* __restrict__ Wfc, const float* __restrict__ bfc,
    float* __restrict__ out, int N)
{
    int g = blockIdx.x;
    int tid = threadIdx.x;
    int w = tid >> 6, lane = tid & 63;
    int lo = lower_bound_i(batch, N, g);
    int hi = lower_bound_i(batch, N, g + 1);
    float sum = 0.f;
    for (int i = lo + w; i < hi; i += 4)
        sum += bf2f(h3[(size_t)i * 64 + lane]);
    __shared__ float P[4][64];
    P[w][lane] = sum;
    __syncthreads();
    if (w == 0) {
        float s = P[0][lane] + P[1][lane] + P[2][lane] + P[3][lane];
        float cnt = (float)((hi - lo) > 0 ? (hi - lo) : 1);
        P[0][lane] = s / cnt;
    }
    __syncthreads();
    if (tid < 11) {
        float s = bfc[tid];
        const float* wr = &Wfc[tid * 64];
        #pragma unroll 8
        for (int k = 0; k < 64; ++k) s += P[0][k] * wr[k];
        out[g * 11 + tid] = s;
    }
}

// ---------------------------------------------------------------------------

extern "C" void kernel_launch(void* const* d_in, const int* in_sizes, int n_in,
                              void* d_out, int out_size, void* d_ws, size_t ws_size,
                              hipStream_t stream) {
    const float* x    = (const float*)d_in[0];
    const int*   ei   = (const int*)d_in[1];
    const int*   batch= (const int*)d_in[2];
    const float* W1   = (const float*)d_in[3];
    const float* b1   = (const float*)d_in[4];
    const float* W2   = (const float*)d_in[5];
    const float* b2   = (const float*)d_in[6];
    const float* W3   = (const float*)d_in[7];
    const float* b3   = (const float*)d_in[8];
    const float* Wfc  = (const float*)d_in[9];
    const float* bfc  = (const float*)d_in[10];
    float* out = (float*)d_out;

    const int N = in_sizes[2];
    const int E = in_sizes[1] / 2;
    const int G = out_size / 11;
    const int* src = ei;
    const int* dst = ei + E;
    const int NB = (N + RB - 1) / RB;      // buckets
    const int NT = NB * NBLK;              // count entries
    const int SB = (NT + SCBS - 1) / SCBS; // scan chunks

    // workspace (all bf16 tables):
    //   B1 64N (h1 -> t3) | B2 64N (buf2 -> h3) | B3 128N (h2) | XB 16N (xb)
    //   then ints: pairs E | eidx E | rowstart N+1 | cnt NT | ofs NT | part
    unsigned short* B1 = (unsigned short*)d_ws;
    unsigned short* B2 = B1 + (size_t)64 * N;
    unsigned short* B3 = B2 + (size_t)64 * N;
    unsigned short* XB = B3 + (size_t)128 * N;
    int* pairs    = (int*)(XB + (size_t)16 * N);
    int* eidx     = pairs + E;
    int* rowstart = eidx + E;
    int* cnt      = rowstart + (N + 1);
    int* ofs      = cnt + NT;
    int* part     = ofs + NT;

    unsigned short* h1   = B1;
    unsigned short* buf2 = B2;
    unsigned short* h2   = B3;
    unsigned short* t3   = B1;   // h1 dead after gather2
    unsigned short* h3   = B2;   // buf2 dead after lin2
    unsigned short* xb   = XB;

    // ---- build: bucket-grouped pairs, then per-bucket CSR ----
    count_kernel<<<NBLK, CFBS, 0, stream>>>(dst, cnt, E, NB);
    scan_k1<<<SB, SCBS, 0, stream>>>(cnt, ofs, part, NT);
    scan_k2<<<1, SCBS, 0, stream>>>(part, SB);
    scan_k3<<<SB, SCBS, 0, stream>>>(ofs, part, NT);
    fillp_kernel<<<NBLK, CFBS, 0, stream>>>(src, dst, ofs, pairs, E, NB);
    bucket_csr_kernel<<<NB, 512, 0, stream>>>(pairs, ofs, rowstart, eidx, N, E, NB);
    xprep_kernel<<<(N + 255) / 256, 256, 0, stream>>>(x, xb, N);

    // ---- layer 1: vectorized 9-dim gather + Lin 9->64 + relu ----
    node1v_kernel<<<(N + 3) / 4, 256, 0, stream>>>(
        xb, rowstart, eidx, W1, b1, h1, N);

    // ---- layer 2 ----
    gather64v_kernel<false><<<(N + 3) / 4, 256, 0, stream>>>(
        h1, rowstart, eidx, nullptr, buf2, N);
    linear_mfma_kernel<64, 128, true><<<(N + 63) / 64, 256, 0, stream>>>(
        buf2, W2, b2, h2, N);

    // ---- layer 3 ----
    linear_mfma_kernel<128, 64, false><<<(N + 63) / 64, 256, 0, stream>>>(
        h2, W3, nullptr, t3, N);
    gather64v_kernel<true><<<(N + 3) / 4, 256, 0, stream>>>(
        t3, rowstart, eidx, b3, h3, N);

    // ---- pool + FC ----
    pool_fc_kernel<<<G, 256, 0, stream>>>(h3, batch, Wfc, bfc, out, N);
}

// Round 9
// 209.644 us; speedup vs baseline: 7.9267x; 1.1131x over previous
//
#include <hip/hip_runtime.h>
#include <hip/hip_bf16.h>

// ---------------------------------------------------------------------------
// GIN (3 layers, eps=0) + global mean pool + FC.
//
// Lessons: r1 global f32 atomics = 64B write-through; r2 per-node CSR fill =
//   105MB dirty lines; r3 block-per-bucket agg = latency collapse; r5 linears
//   LDS-read-bound -> r6 MFMA linears; r7 __shfl in divergent flow = garbage
//   (ds_bpermute only serves ACTIVE lanes); r8 wave-per-node gathers correct
//   but serial-chain-bound (node1v 52us @ 8% HBM, 40% VALU: ~2000cy dependent
//   chain per node, 1 node per wave).
// r9: 4 nodes per wave, chains interleaved. All per-node state in unrolled
//   registers (compile-time indices only); chunk loop OUTER, node loop INNER
//   branchless (clamped shfl src in uniform flow + mask-FMA accumulate) so
//   the scheduler pipelines 4 independent chains.
// ---------------------------------------------------------------------------

#define NBLK 256      // blocks for count/fill
#define CFBS 512      // threads for count/fill
#define RB   128      // nodes per bucket
#define NBMAX 1024    // max buckets (N <= 131072)
#define SCBS 1024     // scan chunk

__device__ inline float bf2f(unsigned short u) {
    return __uint_as_float((unsigned)u << 16);
}
__device__ inline unsigned short f2bf(float f) {
    unsigned x = __float_as_uint(f);
    return (unsigned short)((x + 0x7FFFu + ((x >> 16) & 1u)) >> 16);  // RNE
}
__device__ inline float lo16(unsigned u) { return __uint_as_float(u << 16); }
__device__ inline float hi16(unsigned u) { return __uint_as_float(u & 0xFFFF0000u); }

// ---- bucket build ---------------------------------------------------------

__global__ __launch_bounds__(CFBS) void count_kernel(
    const int* __restrict__ dst, int* __restrict__ cnt, int E, int NB)
{
    __shared__ int hist[NBMAX];
    int tid = threadIdx.x;
    for (int i = tid; i < NBMAX; i += CFBS) hist[i] = 0;
    __syncthreads();
    for (int e = blockIdx.x * CFBS + tid; e < E; e += NBLK * CFBS)
        atomicAdd(&hist[dst[e] >> 7], 1);
    __syncthreads();
    for (int b = tid; b < NB; b += CFBS)
        cnt[b * NBLK + blockIdx.x] = hist[b];
}

__global__ __launch_bounds__(SCBS) void scan_k1(
    const int* __restrict__ cnt, int* __restrict__ ofs,
    int* __restrict__ part, int NT)
{
    __shared__ int tmp[SCBS];
    int i = blockIdx.x * SCBS + threadIdx.x;
    int v = (i < NT) ? cnt[i] : 0;
    tmp[threadIdx.x] = v;
    __syncthreads();
    for (int off = 1; off < SCBS; off <<= 1) {
        int t = (threadIdx.x >= off) ? tmp[threadIdx.x - off] : 0;
        __syncthreads();
        tmp[threadIdx.x] += t;
        __syncthreads();
    }
    if (i < NT) ofs[i] = tmp[threadIdx.x] - v;   // exclusive within chunk
    if (threadIdx.x == SCBS - 1) part[blockIdx.x] = tmp[threadIdx.x];
}

__global__ __launch_bounds__(SCBS) void scan_k2(int* __restrict__ part, int B)
{
    __shared__ int tmp[SCBS];
    int v = (threadIdx.x < B) ? part[threadIdx.x] : 0;
    tmp[threadIdx.x] = v;
    __syncthreads();
    for (int off = 1; off < SCBS; off <<= 1) {
        int t = (threadIdx.x >= off) ? tmp[threadIdx.x - off] : 0;
        __syncthreads();
        tmp[threadIdx.x] += t;
        __syncthreads();
    }
    if (threadIdx.x < B) part[threadIdx.x] = tmp[threadIdx.x] - v;
}

__global__ __launch_bounds__(SCBS) void scan_k3(
    int* __restrict__ ofs, const int* __restrict__ part, int NT)
{
    int i = blockIdx.x * SCBS + threadIdx.x;
    if (i < NT) ofs[i] += part[blockIdx.x];
}

__global__ __launch_bounds__(CFBS) void fillp_kernel(
    const int* __restrict__ src, const int* __restrict__ dst,
    const int* __restrict__ ofs, int* __restrict__ pairs, int E, int NB)
{
    __shared__ int cur[NBMAX];
    int tid = threadIdx.x;
    for (int b = tid; b < NB; b += CFBS)
        cur[b] = ofs[b * NBLK + blockIdx.x];
    __syncthreads();
    for (int e = blockIdx.x * CFBS + tid; e < E; e += NBLK * CFBS) {
        int d = dst[e];
        int b = d >> 7, dl = d & 127;
        int pos = atomicAdd(&cur[b], 1);
        pairs[pos] = (dl << 20) | src[e];
    }
}

// per-bucket CSR finalize: writes land in bucket-local contiguous windows
__global__ __launch_bounds__(512) void bucket_csr_kernel(
    const int* __restrict__ pairs, const int* __restrict__ ofs,
    int* __restrict__ rowstart, int* __restrict__ eidx, int N, int E, int NB)
{
    __shared__ int deg[RB], pfx[RB], cur[RB];
    int tid = threadIdx.x;
    int b = blockIdx.x, n0 = b << 7;
    int e0 = ofs[b * NBLK];
    int e1 = (b + 1 < NB) ? ofs[(b + 1) * NBLK] : E;
    if (tid < RB) deg[tid] = 0;
    __syncthreads();
    for (int e = e0 + tid; e < e1; e += 512)
        atomicAdd(&deg[pairs[e] >> 20], 1);
    __syncthreads();
    if (tid < RB) pfx[tid] = deg[tid];
    __syncthreads();
    for (int off = 1; off < RB; off <<= 1) {
        int t = (tid < RB && tid >= off) ? pfx[tid - off] : 0;
        __syncthreads();
        if (tid < RB) pfx[tid] += t;
        __syncthreads();
    }
    if (tid < RB) {
        int ex = pfx[tid] - deg[tid];     // exclusive
        cur[tid] = ex;
        int n = n0 + tid;
        if (n < N) rowstart[n] = e0 + ex;
    }
    if (b == NB - 1 && tid == 0) rowstart[N] = E;
    __syncthreads();
    for (int e = e0 + tid; e < e1; e += 512) {
        int p = pairs[e];
        int pos = e0 + atomicAdd(&cur[p >> 20], 1);
        eidx[pos] = p & 0xFFFFF;
    }
}

// ---- x prep: xb[N][16] bf16 (pad 9->16) ----------------------------------

__global__ __launch_bounds__(256) void xprep_kernel(
    const float* __restrict__ x, unsigned short* __restrict__ xb, int N)
{
    int n = blockIdx.x * 256 + threadIdx.x;
    if (n >= N) return;
    unsigned short r[16];
    #pragma unroll
    for (int k = 0; k < 9; ++k) r[k] = f2bf(x[(size_t)n * 9 + k]);
    #pragma unroll
    for (int k = 9; k < 16; ++k) r[k] = 0;
    uint4 u0, u1;
    u0.x = r[0] | ((unsigned)r[1] << 16);  u0.y = r[2] | ((unsigned)r[3] << 16);
    u0.z = r[4] | ((unsigned)r[5] << 16);  u0.w = r[6] | ((unsigned)r[7] << 16);
    u1.x = r[8] | ((unsigned)r[9] << 16);  u1.y = 0; u1.z = 0; u1.w = 0;
    *(uint4*)&xb[(size_t)n * 16]     = u0;
    *(uint4*)&xb[(size_t)n * 16 + 8] = u1;
}

// ---- layer 1: 9-dim gather + Lin 9->64 + relu, 4 nodes per wave ----------
// Lane map per node: 16 edge-grp (g) x 4 dim-grp (d4). Branchless inner:
// clamped shfl src (uniform flow) + mask-FMA accumulate.

__global__ __launch_bounds__(256) void node1v_kernel(
    const unsigned short* __restrict__ xb, const int* __restrict__ rs,
    const int* __restrict__ eidx, const float* __restrict__ W1,
    const float* __restrict__ b1, unsigned short* __restrict__ h1, int N)
{
    __shared__ float Wl[576];
    __shared__ float bl[64];
    for (int i = threadIdx.x; i < 576; i += 256) Wl[i] = W1[i];
    if (threadIdx.x < 64) bl[threadIdx.x] = b1[threadIdx.x];
    __syncthreads();
    int wid = threadIdx.x >> 6;
    int lane = threadIdx.x & 63;
    int g  = lane >> 2;     // edge group 0..15
    int d4 = lane & 3;      // dims 4*d4 .. 4*d4+3
    int nb = blockIdx.x * 16 + wid * 4;   // this wave's 4 nodes
    if (nb >= N) return;

    int n[4], e0[4], dg[4];
    float A0[4], A1[4], A2[4], A3[4];
    #pragma unroll
    for (int i = 0; i < 4; ++i) {
        n[i] = min(nb + i, N - 1);
        e0[i] = rs[n[i]];
        dg[i] = rs[n[i] + 1] - e0[i];
        A0[i] = A1[i] = A2[i] = A3[i] = 0.f;
    }
    // self terms (lanes g==0 hold them; duplicated-clamp nodes never stored)
    #pragma unroll
    for (int i = 0; i < 4; ++i) {
        if (g == 0) {
            uint2 u = *(const uint2*)&xb[(size_t)n[i] * 16 + d4 * 4];
            A0[i] += lo16(u.x); A1[i] += hi16(u.x);
            A2[i] += lo16(u.y); A3[i] += hi16(u.y);
        }
    }
    int mdeg = max(max(dg[0], dg[1]), max(dg[2], dg[3]));
    for (int w0 = 0; w0 < mdeg; w0 += 64) {
        int sidx[4], wd[4];
        #pragma unroll
        for (int i = 0; i < 4; ++i) {
            wd[i] = min(max(dg[i] - w0, 0), 64);
            sidx[i] = (lane < wd[i]) ? eidx[e0[i] + w0 + lane] : 0;
        }
        int mwd = max(max(wd[0], wd[1]), max(wd[2], wd[3]));
        for (int c = 0; c < mwd; c += 16) {
            #pragma unroll
            for (int i = 0; i < 4; ++i) {
                int idx = c + g;
                int s = __shfl(sidx[i], idx < wd[i] ? idx : 0); // uniform flow
                float m = (idx < wd[i]) ? 1.f : 0.f;
                uint2 u = *(const uint2*)&xb[(size_t)s * 16 + d4 * 4];
                A0[i] += m * lo16(u.x); A1[i] += m * hi16(u.x);
                A2[i] += m * lo16(u.y); A3[i] += m * hi16(u.y);
            }
        }
    }
    // 4 independent butterflies, stage-major for interleaving
    #pragma unroll
    for (int m = 4; m < 64; m <<= 1) {
        #pragma unroll
        for (int i = 0; i < 4; ++i) {
            A0[i] += __shfl_xor(A0[i], m); A1[i] += __shfl_xor(A1[i], m);
            A2[i] += __shfl_xor(A2[i], m); A3[i] += __shfl_xor(A3[i], m);
        }
    }
    const float* wr = &Wl[lane * 9];
    #pragma unroll
    for (int i = 0; i < 4; ++i) {
        float xv0 = __shfl(A0[i], 0), xv1 = __shfl(A1[i], 0);
        float xv2 = __shfl(A2[i], 0), xv3 = __shfl(A3[i], 0);
        float xv4 = __shfl(A0[i], 1), xv5 = __shfl(A1[i], 1);
        float xv6 = __shfl(A2[i], 1), xv7 = __shfl(A3[i], 1);
        float xv8 = __shfl(A0[i], 2);
        float s = bl[lane] + xv0 * wr[0] + xv1 * wr[1] + xv2 * wr[2]
                + xv3 * wr[3] + xv4 * wr[4] + xv5 * wr[5] + xv6 * wr[6]
                + xv7 * wr[7] + xv8 * wr[8];
        if (nb + i < N)
            h1[(size_t)(nb + i) * 64 + lane] = f2bf(fmaxf(s, 0.f));
    }
}

// ---- 64-dim gather, 4 nodes per wave: 4 edge-grp x 16 dim-grp ------------

template<bool BIAS_RELU>
__global__ __launch_bounds__(256) void gather64v_kernel(
    const unsigned short* __restrict__ feat, const int* __restrict__ rs,
    const int* __restrict__ eidx, const float* __restrict__ bias,
    unsigned short* __restrict__ out, int N)
{
    int wid = threadIdx.x >> 6;
    int lane = threadIdx.x & 63;
    int g  = lane >> 4;     // edge group 0..3
    int d4 = lane & 15;     // dims 4*d4 .. 4*d4+3
    int nb = blockIdx.x * 16 + wid * 4;
    if (nb >= N) return;

    int n[4], e0[4], dg[4];
    float A0[4], A1[4], A2[4], A3[4];
    #pragma unroll
    for (int i = 0; i < 4; ++i) {
        n[i] = min(nb + i, N - 1);
        e0[i] = rs[n[i]];
        dg[i] = rs[n[i] + 1] - e0[i];
        A0[i] = A1[i] = A2[i] = A3[i] = 0.f;
    }
    #pragma unroll
    for (int i = 0; i < 4; ++i) {
        if (g == 0) {       // self term
            uint2 u = *(const uint2*)&feat[(size_t)n[i] * 64 + d4 * 4];
            A0[i] += lo16(u.x); A1[i] += hi16(u.x);
            A2[i] += lo16(u.y); A3[i] += hi16(u.y);
        }
    }
    int mdeg = max(max(dg[0], dg[1]), max(dg[2], dg[3]));
    for (int w0 = 0; w0 < mdeg; w0 += 64) {
        int sidx[4], wd[4];
        #pragma unroll
        for (int i = 0; i < 4; ++i) {
            wd[i] = min(max(dg[i] - w0, 0), 64);
            sidx[i] = (lane < wd[i]) ? eidx[e0[i] + w0 + lane] : 0;
        }
        int mwd = max(max(wd[0], wd[1]), max(wd[2], wd[3]));
        for (int c = 0; c < mwd; c += 8) {
            #pragma unroll
            for (int i = 0; i < 4; ++i) {
                int i0 = c + g, i1 = c + 4 + g;
                int s0 = __shfl(sidx[i], i0 < wd[i] ? i0 : 0);  // uniform flow
                int s1 = __shfl(sidx[i], i1 < wd[i] ? i1 : 0);
                float m0 = (i0 < wd[i]) ? 1.f : 0.f;
                float m1 = (i1 < wd[i]) ? 1.f : 0.f;
                uint2 u0 = *(const uint2*)&feat[(size_t)s0 * 64 + d4 * 4];
                uint2 u1 = *(const uint2*)&feat[(size_t)s1 * 64 + d4 * 4];
                A0[i] += m0 * lo16(u0.x) + m1 * lo16(u1.x);
                A1[i] += m0 * hi16(u0.x) + m1 * hi16(u1.x);
                A2[i] += m0 * lo16(u0.y) + m1 * lo16(u1.y);
                A3[i] += m0 * hi16(u0.y) + m1 * hi16(u1.y);
            }
        }
    }
    #pragma unroll
    for (int m = 16; m < 64; m <<= 1) {
        #pragma unroll
        for (int i = 0; i < 4; ++i) {
            A0[i] += __shfl_xor(A0[i], m); A1[i] += __shfl_xor(A1[i], m);
            A2[i] += __shfl_xor(A2[i], m); A3[i] += __shfl_xor(A3[i], m);
        }
    }
    float4 bv = make_float4(0.f, 0.f, 0.f, 0.f);
    if (BIAS_RELU) bv = *(const float4*)&bias[d4 * 4];
    #pragma unroll
    for (int i = 0; i < 4; ++i) {
        if (g == 0 && nb + i < N) {
            float a0 = A0[i], a1 = A1[i], a2 = A2[i], a3 = A3[i];
            if (BIAS_RELU) {
                a0 = fmaxf(a0 + bv.x, 0.f); a1 = fmaxf(a1 + bv.y, 0.f);
                a2 = fmaxf(a2 + bv.z, 0.f); a3 = fmaxf(a3 + bv.w, 0.f);
            }
            ushort4 u;
            u.x = f2bf(a0); u.y = f2bf(a1); u.z = f2bf(a2); u.w = f2bf(a3);
            *(ushort4*)&out[(size_t)(nb + i) * 64 + d4 * 4] = u;
        }
    }
}

// ---- MFMA linear: Y[n,:OUT] = relu?(A[n,:IN] @ W^T + bias), bf16 tables ---

template<int IN, int OUT, bool RELU>
__global__ __launch_bounds__(256) void linear_mfma_kernel(
    const unsigned short* __restrict__ A, const float* __restrict__ W,
    const float* __restrict__ bias, unsigned short* __restrict__ Y, int N)
{
    using s8v = __attribute__((ext_vector_type(8))) short;
    using f4v = __attribute__((ext_vector_type(4))) float;
    constexpr int KT = IN / 32;       // K-steps
    constexpr int CT = OUT / 16;      // col tiles
    constexpr int INP = IN + 8;       // padded row stride (ushorts)
    __shared__ __align__(16) unsigned short Wb[OUT * INP];
    __shared__ float bl[OUT];
    int tid = threadIdx.x;
    for (int i = tid; i < OUT * IN; i += 256) {
        int o = i / IN, k = i % IN;
        Wb[o * INP + k] = f2bf(W[i]);
    }
    for (int i = tid; i < OUT; i += 256) bl[i] = bias ? bias[i] : 0.f;
    __syncthreads();

    int w = tid >> 6, lane = tid & 63;
    int n0 = blockIdx.x * 64 + w * 16;
    int hl = lane >> 4;               // k-slice 0..3
    int ll = lane & 15;               // row (A) / col (B)

    int an = n0 + ll;
    if (an >= N) an = N - 1;          // clamp: garbage rows never written
    const unsigned short* arow = &A[(size_t)an * IN + hl * 8];
    s8v a[KT];
    #pragma unroll
    for (int ks = 0; ks < KT; ++ks) a[ks] = *(const s8v*)&arow[ks * 32];

    f4v acc[CT];
    #pragma unroll
    for (int c = 0; c < CT; ++c) acc[c] = (f4v){0.f, 0.f, 0.f, 0.f};
    #pragma unroll
    for (int c = 0; c < CT; ++c) {
        const unsigned short* wrow = &Wb[(c * 16 + ll) * INP + hl * 8];
        #pragma unroll
        for (int ks = 0; ks < KT; ++ks) {
            s8v b = *(const s8v*)&wrow[ks * 32];
            acc[c] = __builtin_amdgcn_mfma_f32_16x16x32_bf16(a[ks], b, acc[c], 0, 0, 0);
        }
    }
    #pragma unroll
    for (int c = 0; c < CT; ++c) {
        int col = c * 16 + ll;
        float bv = bl[col];
        #pragma unroll
        for (int r = 0; r < 4; ++r) {
            int gn = n0 + hl * 4 + r;
            if (gn < N) {
                float v = acc[c][r] + bv;
                if (RELU) v = fmaxf(v, 0.f);
                Y[(size_t)gn * OUT + col] = f2bf(v);
            }
        }
    }
}

// ---- pool + FC ------------------------------------------------------------

__device__ inline int lower_bound_i(const int* a, int n, int v) {
    int lo = 0, hi = n;
    while (lo < hi) {
        int mid = (lo + hi) >> 1;
        if (a[mid] < v) lo = mid + 1; else hi = mid;
    }
    return lo;
}

__global__ __launch_bounds__(256) void pool_fc_kernel(
    const unsigned short* __restrict__ h3, const int* __restrict__ batch,
    const float* __restrict__ Wfc, const float* __restrict__ bfc,
    float* __restrict__ out, int N)
{
    int g = blockIdx.x;
    int tid = threadIdx.x;
    int w = tid >> 6, lane = tid & 63;
    int lo = lower_bound_i(batch, N, g);
    int hi = lower_bound_i(batch, N, g + 1);
    float sum = 0.f;
    for (int i = lo + w; i < hi; i += 4)
        sum += bf2f(h3[(size_t)i * 64 + lane]);
    __shared__ float P[4][64];
    P[w][lane] = sum;
    __syncthreads();
    if (w == 0) {
        float s = P[0][lane] + P[1][lane] + P[2][lane] + P[3][lane];
        float cnt = (float)((hi - lo) > 0 ? (hi - lo) : 1);
        P[0][lane] = s / cnt;
    }
    __syncthreads();
    if (tid < 11) {
        float s = bfc[tid];
        const float* wr = &Wfc[tid * 64];
        #pragma unroll 8
        for (int k = 0; k < 64; ++k) s += P[0][k] * wr[k];
        out[g * 11 + tid] = s;
    }
}

// ---------------------------------------------------------------------------

extern "C" void kernel_launch(void* const* d_in, const int* in_sizes, int n_in,
                              void* d_out, int out_size, void* d_ws, size_t ws_size,
                              hipStream_t stream) {
    const float* x    = (const float*)d_in[0];
    const int*   ei   = (const int*)d_in[1];
    const int*   batch= (const int*)d_in[2];
    const float* W1   = (const float*)d_in[3];
    const float* b1   = (const float*)d_in[4];
    const float* W2   = (const float*)d_in[5];
    const float* b2   = (const float*)d_in[6];
    const float* W3   = (const float*)d_in[7];
    const float* b3   = (const float*)d_in[8];
    const float* Wfc  = (const float*)d_in[9];
    const float* bfc  = (const float*)d_in[10];
    float* out = (float*)d_out;

    const int N = in_sizes[2];
    const int E = in_sizes[1] / 2;
    const int G = out_size / 11;
    const int* src = ei;
    const int* dst = ei + E;
    const int NB = (N + RB - 1) / RB;      // buckets
    const int NT = NB * NBLK;              // count entries
    const int SB = (NT + SCBS - 1) / SCBS; // scan chunks

    // workspace (all bf16 tables):
    //   B1 64N (h1 -> t3) | B2 64N (buf2 -> h3) | B3 128N (h2) | XB 16N (xb)
    //   then ints: pairs E | eidx E | rowstart N+1 | cnt NT | ofs NT | part
    unsigned short* B1 = (unsigned short*)d_ws;
    unsigned short* B2 = B1 + (size_t)64 * N;
    unsigned short* B3 = B2 + (size_t)64 * N;
    unsigned short* XB = B3 + (size_t)128 * N;
    int* pairs    = (int*)(XB + (size_t)16 * N);
    int* eidx     = pairs + E;
    int* rowstart = eidx + E;
    int* cnt      = rowstart + (N + 1);
    int* ofs      = cnt + NT;
    int* part     = ofs + NT;

    unsigned short* h1   = B1;
    unsigned short* buf2 = B2;
    unsigned short* h2   = B3;
    unsigned short* t3   = B1;   // h1 dead after gather2
    unsigned short* h3   = B2;   // buf2 dead after lin2
    unsigned short* xb   = XB;

    // ---- build: bucket-grouped pairs, then per-bucket CSR ----
    count_kernel<<<NBLK, CFBS, 0, stream>>>(dst, cnt, E, NB);
    scan_k1<<<SB, SCBS, 0, stream>>>(cnt, ofs, part, NT);
    scan_k2<<<1, SCBS, 0, stream>>>(part, SB);
    scan_k3<<<SB, SCBS, 0, stream>>>(ofs, part, NT);
    fillp_kernel<<<NBLK, CFBS, 0, stream>>>(src, dst, ofs, pairs, E, NB);
    bucket_csr_kernel<<<NB, 512, 0, stream>>>(pairs, ofs, rowstart, eidx, N, E, NB);
    xprep_kernel<<<(N + 255) / 256, 256, 0, stream>>>(x, xb, N);

    // ---- layer 1: vectorized 9-dim gather + Lin 9->64 + relu ----
    node1v_kernel<<<(N + 15) / 16, 256, 0, stream>>>(
        xb, rowstart, eidx, W1, b1, h1, N);

    // ---- layer 2 ----
    gather64v_kernel<false><<<(N + 15) / 16, 256, 0, stream>>>(
        h1, rowstart, eidx, nullptr, buf2, N);
    linear_mfma_kernel<64, 128, true><<<(N + 63) / 64, 256, 0, stream>>>(
        buf2, W2, b2, h2, N);

    // ---- layer 3 ----
    linear_mfma_kernel<128, 64, false><<<(N + 63) / 64, 256, 0, stream>>>(
        h2, W3, nullptr, t3, N);
    gather64v_kernel<true><<<(N + 15) / 16, 256, 0, stream>>>(
        t3, rowstart, eidx, b3, h3, N);

    // ---- pool + FC ----
    pool_fc_kernel<<<G, 256, 0, stream>>>(h3, batch, Wfc, bfc, out, N);
}